// Round 2
// baseline (574.911 us; speedup 1.0000x reference)
//
#include <hip/hip_runtime.h>

typedef float f32x4 __attribute__((ext_vector_type(4)));
typedef __bf16 bf16x8 __attribute__((ext_vector_type(8)));
typedef __bf16 bf16x4 __attribute__((ext_vector_type(4)));

#define HIDDEN 128

// ---- workspace layout: bf16 weight-fragment region, then f32 region ----
#define WB_W1E 0
#define WB_W2E 4096
#define WB_W3E 20480
#define WB_W1N 22528
#define WB_W2N 26624
#define WB_W3N 43008
#define WB_W1D 45056
#define WB_W2D 49152
#define WB_W3D 65536
#define WB_W4D 81920
#define WB_TOTAL 83968

// ================= weight prep: f32 row-major [K][N] -> fragmented bf16 =================
// frag fi = kt*CT+ct, within frag lane-major 8 elems:
//   value = W[kt*32 + (lane>>4)*8 + j][ct*16 + (lane&15)]  (zero-padded)
// bias fold: row k==Ks[seg] holds the layer-1 bias (input slot fed with 1.0)
__global__ void k_prep(const float* __restrict__ ew1, const float* __restrict__ eb1,
                       const float* __restrict__ ew2, const float* __restrict__ ew3,
                       const float* __restrict__ nw1, const float* __restrict__ nb1,
                       const float* __restrict__ nw2, const float* __restrict__ nw3,
                       const float* __restrict__ dw1, const float* __restrict__ db1,
                       const float* __restrict__ dw2, const float* __restrict__ dw3,
                       const float* __restrict__ dw4, __bf16* __restrict__ wb) {
  int gid = blockIdx.x * 256 + threadIdx.x;
  if (gid >= WB_TOTAL) return;
  const float* srcs[10] = {ew1, ew2, ew3, nw1, nw2, nw3, dw1, dw2, dw3, dw4};
  const float* brow[10] = {eb1, 0, 0, nb1, 0, 0, db1, 0, 0, 0};
  const int Ks[10] = {9, 128, 128, 5, 128, 128, 5, 128, 128, 128};
  const int Ns[10] = {128, 128, 3, 128, 128, 1, 128, 128, 128, 1};
  const int CTs[10] = {8, 8, 1, 8, 8, 1, 8, 8, 8, 1};
  const int cum[11] = {0, 4096, 20480, 22528, 26624, 43008, 45056, 49152, 65536, 81920, 83968};
  int seg = 0;
  while (gid >= cum[seg + 1]) seg++;
  int li = gid - cum[seg];
  int j = li & 7;
  int lane = (li >> 3) & 63;
  int fi = li >> 9;
  int CT = CTs[seg];
  int ct = fi % CT;
  int kt = fi / CT;
  int k = kt * 32 + ((lane >> 4) << 3) + j;
  int n = ct * 16 + (lane & 15);
  float v = 0.f;
  if (n < Ns[seg]) {
    if (k < Ks[seg]) v = srcs[seg][k * Ns[seg] + n];
    else if (brow[seg] && k == Ks[seg]) v = brow[seg][n];
  }
  wb[gid] = (__bf16)v;
}

// ================= init =================
__global__ void k_init_nodes(const float* __restrict__ y_prev, float* __restrict__ x4,
                             float* __restrict__ deg, float* __restrict__ aggr, int n) {
  int i = blockIdx.x * 256 + threadIdx.x;
  if (i < n) {
    x4[i] = y_prev[i];
    deg[i] = 0.f;
    f32x4 z = {0.f, 0.f, 0.f, 0.f};
    *(f32x4*)(aggr + 4 * i) = z;
  }
}

__global__ void k_init_edges(const float* __restrict__ Xc, const float* __restrict__ y_prev,
                             const int* __restrict__ src, const int* __restrict__ dstp,
                             float* __restrict__ pe, float* __restrict__ ea,
                             float* __restrict__ deg, int E) {
  int e = blockIdx.x * 256 + threadIdx.x;
  if (e < E) {
    int s = src[e], d = dstp[e];
    float dx = Xc[d * 6 + 0] - Xc[s * 6 + 0];
    float dy = Xc[d * 6 + 1] - Xc[s * 6 + 1];
    float dz = Xc[d * 6 + 2] - Xc[s * 6 + 2];
    float nr = sqrtf(dx * dx + dy * dy + dz * dz);
    f32x4 p = {dx, dy, dz, nr};
    *(f32x4*)(pe + 4 * e) = p;
    float w = y_prev[d] - y_prev[s];
    f32x4 a = {w * dx, w * dy, w * dz, 0.f};
    *(f32x4*)(ea + 4 * e) = a;
    atomicAdd(deg + d, 1.0f);
  }
}

// ================= MFMA helpers (swapped operands: D = W_frag x act_frag = h^T) =================
// act LDS layout: [16 edge rows][128 h] bf16, row stride 256B, XOR-swizzled byte ^ ((row&7)<<4)
// D-frag: lane l holds h[e=l&15][n = ct*16 + (l>>4)*4 + r]

__device__ __forceinline__ void pinv(bf16x8& v) { asm volatile("" : "+v"(v)); }

__device__ __forceinline__ void load_res8(const __bf16* __restrict__ Wf, int lane,
                                          bf16x8 (&wr)[4][8]) {
#pragma unroll
  for (int kt = 0; kt < 4; kt++)
#pragma unroll
    for (int ct = 0; ct < 8; ct++)
      wr[kt][ct] = *(const bf16x8*)(Wf + ((kt * 8 + ct) << 9) + lane * 8);
}

__device__ __forceinline__ void load_res1(const __bf16* __restrict__ Wf, int lane,
                                          bf16x8 (&wr)[4]) {
#pragma unroll
  for (int kt = 0; kt < 4; kt++) wr[kt] = *(const bf16x8*)(Wf + (kt << 9) + lane * 8);
}

__device__ __forceinline__ bf16x8 read_act(const char* actb, int col, int krow, int kt) {
  int off = (col * 256 + kt * 64 + krow * 16) ^ ((col & 7) << 4);
  return *(const bf16x8*)(actb + off);
}

// relu + stage h^T: lane writes 4 consecutive h of its edge row as one b64
__device__ __forceinline__ void stage_relu_T(char* actb, int col, int krow,
                                             const f32x4 (&acc)[8]) {
#pragma unroll
  for (int ct = 0; ct < 8; ct++) {
    bf16x4 p;
#pragma unroll
    for (int r = 0; r < 4; r++) {
      float v = acc[ct][r];
      p[r] = (__bf16)(v > 0.f ? v : 0.f);
    }
    *(bf16x4*)(actb + ((col * 256 + ct * 32 + krow * 8) ^ ((col & 7) << 4))) = p;
  }
}

__device__ __forceinline__ void layer1_gA(const char* actb, int col, int krow, int lane,
                                          const __bf16* __restrict__ W1f, f32x4 (&acc)[8]) {
  bf16x8 b = read_act(actb, col, krow, 0);
#pragma unroll
  for (int ct = 0; ct < 8; ct++) {
    bf16x8 a = *(const bf16x8*)(W1f + (ct << 9) + lane * 8);
    acc[ct] = __builtin_amdgcn_mfma_f32_16x16x32_bf16(a, b, acc[ct], 0, 0, 0);
  }
}

__device__ __forceinline__ void layer_rB(const char* actb, int col, int krow,
                                         const bf16x8 (&wr)[4][8], f32x4 (&acc)[8]) {
#pragma unroll
  for (int kt = 0; kt < 4; kt++) {
    bf16x8 b = read_act(actb, col, krow, kt);
#pragma unroll
    for (int ct = 0; ct < 8; ct++)
      acc[ct] = __builtin_amdgcn_mfma_f32_16x16x32_bf16(wr[kt][ct], b, acc[ct], 0, 0, 0);
  }
}

__device__ __forceinline__ void layer_gA(const char* actb, int col, int krow, int lane,
                                         const __bf16* __restrict__ Wf, f32x4 (&acc)[8]) {
#pragma unroll
  for (int kt = 0; kt < 4; kt++) {
    bf16x8 b = read_act(actb, col, krow, kt);
#pragma unroll
    for (int ct = 0; ct < 8; ct++) {
      bf16x8 a = *(const bf16x8*)(Wf + ((kt * 8 + ct) << 9) + lane * 8);
      acc[ct] = __builtin_amdgcn_mfma_f32_16x16x32_bf16(a, b, acc[ct], 0, 0, 0);
    }
  }
}

template <int KT>
__device__ __forceinline__ f32x4 out_rB(const char* actb, int col, int krow,
                                        const bf16x8 (&wr)[4], f32x4 acc) {
#pragma unroll
  for (int kt = 0; kt < KT; kt++) {
    bf16x8 b = read_act(actb, col, krow, kt);
    acc = __builtin_amdgcn_mfma_f32_16x16x32_bf16(wr[kt], b, acc, 0, 0, 0);
  }
  return acc;
}

// stage the 16x32 input block: lanes<16 write k0..15 (w0,w1), lanes 16..31 zero k16..31
__device__ __forceinline__ void stage_input(char* actb, int l, bf16x8 w0, bf16x8 w1) {
  if (l < 16) {
    int sw = (l & 7) << 4;
    *(bf16x8*)(actb + ((l * 256 + 0) ^ sw)) = w0;
    *(bf16x8*)(actb + ((l * 256 + 16) ^ sw)) = w1;
  } else if (l < 32) {
    int r = l - 16;
    int sw = (r & 7) << 4;
    bf16x8 zz;
#pragma unroll
    for (int q = 0; q < 8; q++) zz[q] = (__bf16)0.f;
    *(bf16x8*)(actb + ((r * 256 + 32) ^ sw)) = zz;
    *(bf16x8*)(actb + ((r * 256 + 48) ^ sw)) = zz;
  }
}

// ================= edge pass =================
struct ED {
  int s, d;
  f32x4 pe4, ea4;
};

__device__ __forceinline__ ED load_ed(int tile, int col, int E, const int* __restrict__ src,
                                      const int* __restrict__ dstp, const float* __restrict__ pe,
                                      const float* __restrict__ ea) {
  int e = tile * 16 + col;
  if (e >= E) e = E - 1;
  ED r;
  r.s = src[e];
  r.d = dstp[e];
  r.pe4 = *(const f32x4*)(pe + 4 * e);
  r.ea4 = *(const f32x4*)(ea + 4 * e);
  return r;
}

__global__ __launch_bounds__(256, 2) void k_edge(
    const float* __restrict__ x4, const float* __restrict__ pe, float* __restrict__ ea,
    const int* __restrict__ src, const int* __restrict__ dstp, const __bf16* __restrict__ W1f,
    const __bf16* __restrict__ W2f, const __bf16* __restrict__ W3f, const float* __restrict__ b2,
    const float* __restrict__ b3, float* __restrict__ aggr, int ntiles, int E) {
  __shared__ char act[4][4096];
  int l = threadIdx.x & 63;
  int widx = threadIdx.x >> 6;
  char* actb = act[widx];
  int col = l & 15, krow = l >> 4;
  int wgid = blockIdx.x * 4 + widx;
  int nw = gridDim.x * 4;

  bf16x8 w2r[4][8];
  load_res8(W2f, l, w2r);
  bf16x8 w3r[4];
  load_res1(W3f, l, w3r);
#pragma unroll
  for (int kt = 0; kt < 4; kt++) {
#pragma unroll
    for (int ct = 0; ct < 8; ct++) pinv(w2r[kt][ct]);
    pinv(w3r[kt]);
  }

  f32x4 b3v;
  b3v[0] = b3[0];
  b3v[1] = b3[1];
  b3v[2] = b3[2];
  b3v[3] = 0.f;

  int tile = wgid;
  ED cur;
  float xs4 = 0.f, xd4 = 0.f;
  if (tile < ntiles) {
    cur = load_ed(tile, col, E, src, dstp, pe, ea);
    xs4 = x4[cur.s];
    xd4 = x4[cur.d];
  }

  while (tile < ntiles) {
    int nt = tile + nw;
    ED nxt = cur;
    if (nt < ntiles) nxt = load_ed(nt, col, E, src, dstp, pe, ea);
    float xs4n = x4[nxt.s];
    float xd4n = x4[nxt.d];
    int e0 = tile * 16;

    // stage net_in = [disp(3), norm, ea(3), xs4, xd4, 1(bias)] rows 0..15
    bf16x8 w0, w1;
    w0[0] = (__bf16)cur.pe4[0];
    w0[1] = (__bf16)cur.pe4[1];
    w0[2] = (__bf16)cur.pe4[2];
    w0[3] = (__bf16)cur.pe4[3];
    w0[4] = (__bf16)cur.ea4[0];
    w0[5] = (__bf16)cur.ea4[1];
    w0[6] = (__bf16)cur.ea4[2];
    w0[7] = (__bf16)xs4;
#pragma unroll
    for (int q = 0; q < 8; q++) w1[q] = (__bf16)0.f;
    w1[0] = (__bf16)xd4;
    w1[1] = (__bf16)1.0f;
    stage_input(actb, l, w0, w1);

    // layer 1 (bias folded via 1-slot)
    f32x4 h[8];
#pragma unroll
    for (int ct = 0; ct < 8; ct++) {
      f32x4 z = {0.f, 0.f, 0.f, 0.f};
      h[ct] = z;
    }
    layer1_gA(actb, col, krow, l, W1f, h);
    stage_relu_T(actb, col, krow, h);

    // layer 2 (resident weights, per-tile bias vec loads)
#pragma unroll
    for (int ct = 0; ct < 8; ct++) h[ct] = *(const f32x4*)(b2 + ct * 16 + krow * 4);
    layer_rB(actb, col, krow, w2r, h);
    stage_relu_T(actb, col, krow, h);

    // layer 3 (128 -> 3)
    f32x4 o = out_rB<4>(actb, col, krow, w3r, b3v);

    // epilogue: lane e<16 owns edge e: vectorized ea update + 3 atomics
    if (l < 16) {
      int ee = e0 + l;
      if (ee < E) {
        f32x4 nv = cur.ea4;
        nv[0] += o[0];
        nv[1] += o[1];
        nv[2] += o[2];
        *(f32x4*)(ea + 4 * ee) = nv;
        int d4 = cur.d * 4;
        atomicAdd(aggr + d4 + 0, nv[0]);
        atomicAdd(aggr + d4 + 1, nv[1]);
        atomicAdd(aggr + d4 + 2, nv[2]);
      }
    }
    tile = nt;
    cur = nxt;
    xs4 = xs4n;
    xd4 = xd4n;
  }
}

// ================= node pass =================
__global__ __launch_bounds__(256, 2) void k_node(
    float* __restrict__ x4, const float* __restrict__ Xc, float* __restrict__ aggr,
    const float* __restrict__ deg, const __bf16* __restrict__ W1f,
    const __bf16* __restrict__ W2f, const __bf16* __restrict__ W3f, const float* __restrict__ b2,
    const float* __restrict__ b3, int ntiles, int n) {
  __shared__ char act[4][4096];
  int l = threadIdx.x & 63;
  int widx = threadIdx.x >> 6;
  char* actb = act[widx];
  int col = l & 15, krow = l >> 4;
  int wgid = blockIdx.x * 4 + widx;
  int nw = gridDim.x * 4;

  bf16x8 w2r[4][8];
  load_res8(W2f, l, w2r);
  bf16x8 w3r[4];
  load_res1(W3f, l, w3r);
#pragma unroll
  for (int kt = 0; kt < 4; kt++) {
#pragma unroll
    for (int ct = 0; ct < 8; ct++) pinv(w2r[kt][ct]);
    pinv(w3r[kt]);
  }
  float b3s = b3[0];

  for (int tile = wgid; tile < ntiles; tile += nw) {
    int i0 = tile * 16 + col;
    bool vi = i0 < n;
    int i = vi ? i0 : (n - 1);
    float x3 = Xc[i * 6 + 4];
    float xv = x4[i];
    f32x4 ag = *(const f32x4*)(aggr + 4 * i);
    float dg = deg[i];
    float inv = dg > 0.f ? 1.0f / dg : 0.f;

    if (l < 16 && vi) {
      f32x4 z = {0.f, 0.f, 0.f, 0.f};
      *(f32x4*)(aggr + 4 * i) = z;  // clear for next iteration
    }

    bf16x8 w0, w1;
#pragma unroll
    for (int q = 0; q < 8; q++) w1[q] = (__bf16)0.f;
    w0 = w1;
    w0[0] = (__bf16)x3;
    w0[1] = (__bf16)xv;
    w0[2] = (__bf16)(ag[0] * inv);
    w0[3] = (__bf16)(ag[1] * inv);
    w0[4] = (__bf16)(ag[2] * inv);
    w0[5] = (__bf16)1.0f;
    stage_input(actb, l, w0, w1);

    f32x4 h[8];
#pragma unroll
    for (int ct = 0; ct < 8; ct++) {
      f32x4 z = {0.f, 0.f, 0.f, 0.f};
      h[ct] = z;
    }
    layer1_gA(actb, col, krow, l, W1f, h);
    stage_relu_T(actb, col, krow, h);

#pragma unroll
    for (int ct = 0; ct < 8; ct++) h[ct] = *(const f32x4*)(b2 + ct * 16 + krow * 4);
    layer_rB(actb, col, krow, w2r, h);
    stage_relu_T(actb, col, krow, h);

    f32x4 ob;
    ob[0] = ob[1] = ob[2] = ob[3] = b3s;
    f32x4 o = out_rB<4>(actb, col, krow, w3r, ob);

    if (l < 16 && vi) x4[i0] = xv + o[0];
  }
}

// ================= decoder =================
__global__ __launch_bounds__(256, 2) void k_dec(
    const float* __restrict__ x4, const float* __restrict__ Xc, const float* __restrict__ y_prev,
    const __bf16* __restrict__ W1f, const __bf16* __restrict__ W2f,
    const __bf16* __restrict__ W3f, const __bf16* __restrict__ W4f, const float* __restrict__ b2,
    const float* __restrict__ b3, const float* __restrict__ b4, float* __restrict__ out,
    int ntiles, int n) {
  __shared__ char act[4][4096];
  int l = threadIdx.x & 63;
  int widx = threadIdx.x >> 6;
  char* actb = act[widx];
  int col = l & 15, krow = l >> 4;
  int wgid = blockIdx.x * 4 + widx;
  int nw = gridDim.x * 4;

  bf16x8 w2r[4][8];
  load_res8(W2f, l, w2r);
  bf16x8 w4r[4];
  load_res1(W4f, l, w4r);
#pragma unroll
  for (int kt = 0; kt < 4; kt++) {
#pragma unroll
    for (int ct = 0; ct < 8; ct++) pinv(w2r[kt][ct]);
    pinv(w4r[kt]);
  }
  float b4s = b4[0];

  for (int tile = wgid; tile < ntiles; tile += nw) {
    int i0 = tile * 16 + col;
    bool vi = i0 < n;
    int i = vi ? i0 : (n - 1);

    bf16x8 w0, w1;
#pragma unroll
    for (int q = 0; q < 8; q++) w1[q] = (__bf16)0.f;
    w0 = w1;
    w0[0] = (__bf16)Xc[i * 6 + 0];
    w0[1] = (__bf16)Xc[i * 6 + 1];
    w0[2] = (__bf16)Xc[i * 6 + 2];
    w0[3] = (__bf16)Xc[i * 6 + 4];
    w0[4] = (__bf16)x4[i];
    w0[5] = (__bf16)1.0f;
    stage_input(actb, l, w0, w1);

    f32x4 h[8];
#pragma unroll
    for (int ct = 0; ct < 8; ct++) {
      f32x4 z = {0.f, 0.f, 0.f, 0.f};
      h[ct] = z;
    }
    layer1_gA(actb, col, krow, l, W1f, h);
    stage_relu_T(actb, col, krow, h);

#pragma unroll
    for (int ct = 0; ct < 8; ct++) h[ct] = *(const f32x4*)(b2 + ct * 16 + krow * 4);
    layer_rB(actb, col, krow, w2r, h);
    stage_relu_T(actb, col, krow, h);

#pragma unroll
    for (int ct = 0; ct < 8; ct++) h[ct] = *(const f32x4*)(b3 + ct * 16 + krow * 4);
    layer_gA(actb, col, krow, l, W3f, h);
    stage_relu_T(actb, col, krow, h);

    f32x4 ob;
    ob[0] = ob[1] = ob[2] = ob[3] = b4s;
    f32x4 o = out_rB<4>(actb, col, krow, w4r, ob);

    if (l < 16 && vi) out[i0] = y_prev[i0] + o[0];
  }
}

// ================= host =================
extern "C" void kernel_launch(void* const* d_in, const int* in_sizes, int n_in, void* d_out,
                              int out_size, void* d_ws, size_t ws_size, hipStream_t stream) {
  const float* Xc = (const float*)d_in[0];
  const float* y_prev = (const float*)d_in[1];
  const int* edge = (const int*)d_in[2];
  const float* ew1 = (const float*)d_in[4];
  const float* eb1 = (const float*)d_in[5];
  const float* ew2 = (const float*)d_in[6];
  const float* eb2 = (const float*)d_in[7];
  const float* ew3 = (const float*)d_in[8];
  const float* eb3 = (const float*)d_in[9];
  const float* nw1 = (const float*)d_in[10];
  const float* nb1 = (const float*)d_in[11];
  const float* nw2 = (const float*)d_in[12];
  const float* nb2 = (const float*)d_in[13];
  const float* nw3 = (const float*)d_in[14];
  const float* nb3 = (const float*)d_in[15];
  const float* dw1 = (const float*)d_in[16];
  const float* db1 = (const float*)d_in[17];
  const float* dw2 = (const float*)d_in[18];
  const float* db2 = (const float*)d_in[19];
  const float* dw3 = (const float*)d_in[20];
  const float* db3 = (const float*)d_in[21];
  const float* dw4 = (const float*)d_in[22];
  const float* db4 = (const float*)d_in[23];

  int n = in_sizes[0] / 6;
  int E = in_sizes[2] / 2;
  const int* srcp = edge;
  const int* dstp = edge + E;

  __bf16* wb = (__bf16*)d_ws;
  float* fbase = (float*)((char*)d_ws + (size_t)WB_TOTAL * 2);
  size_t na = ((size_t)n + 3) & ~(size_t)3;
  float* x4 = fbase;
  float* deg = fbase + na;
  float* aggr = fbase + 2 * na;
  float* pe = fbase + 6 * na;
  float* ea = fbase + 6 * na + 4 * (size_t)E;

  size_t need = (size_t)WB_TOTAL * 2 + (6 * na + 8 * (size_t)E) * 4;
  if (ws_size < need) return;

  dim3 B(256);
  k_prep<<<dim3((WB_TOTAL + 255) / 256), B, 0, stream>>>(ew1, eb1, ew2, ew3, nw1, nb1, nw2, nw3,
                                                         dw1, db1, dw2, dw3, dw4, wb);
  k_init_nodes<<<dim3((n + 255) / 256), B, 0, stream>>>(y_prev, x4, deg, aggr, n);
  k_init_edges<<<dim3((E + 255) / 256), B, 0, stream>>>(Xc, y_prev, srcp, dstp, pe, ea, deg, E);

  int etiles = (E + 15) / 16;
  int vtiles = (n + 15) / 16;
  for (int it = 0; it < 3; it++) {
    k_edge<<<dim3(512), B, 0, stream>>>(x4, pe, ea, srcp, dstp, wb + WB_W1E, wb + WB_W2E,
                                        wb + WB_W3E, eb2, eb3, aggr, etiles, E);
    k_node<<<dim3(512), B, 0, stream>>>(x4, Xc, aggr, deg, wb + WB_W1N, wb + WB_W2N, wb + WB_W3N,
                                        nb2, nb3, vtiles, n);
  }
  k_dec<<<dim3(512), B, 0, stream>>>(x4, Xc, y_prev, wb + WB_W1D, wb + WB_W2D, wb + WB_W3D,
                                     wb + WB_W4D, db2, db3, db4, (float*)d_out, vtiles, n);
}

// Round 3
// 504.160 us; speedup vs baseline: 1.1403x; 1.1403x over previous
//
#include <hip/hip_runtime.h>

typedef float f32x4 __attribute__((ext_vector_type(4)));
typedef __bf16 bf16x8 __attribute__((ext_vector_type(8)));
typedef __bf16 bf16x4 __attribute__((ext_vector_type(4)));

#define HIDDEN 128

// ---- workspace layout: bf16 weight-fragment region, then f32 region ----
#define WB_W1E 0
#define WB_W2E 4096
#define WB_W3E 20480
#define WB_W1N 22528
#define WB_W2N 26624
#define WB_W3N 43008
#define WB_W1D 45056
#define WB_W2D 49152
#define WB_W3D 65536
#define WB_W4D 81920
#define WB_TOTAL 83968

// ================= weight prep: f32 row-major [K][N] -> fragmented bf16 =================
// frag fi = kt*CT+ct, within frag lane-major 8 elems:
//   value = W[kt*32 + (lane>>4)*8 + j][ct*16 + (lane&15)]  (zero-padded)
// bias fold: row k==Ks[seg] holds the layer-1 bias (input slot fed with 1.0)
__global__ void k_prep(const float* __restrict__ ew1, const float* __restrict__ eb1,
                       const float* __restrict__ ew2, const float* __restrict__ ew3,
                       const float* __restrict__ nw1, const float* __restrict__ nb1,
                       const float* __restrict__ nw2, const float* __restrict__ nw3,
                       const float* __restrict__ dw1, const float* __restrict__ db1,
                       const float* __restrict__ dw2, const float* __restrict__ dw3,
                       const float* __restrict__ dw4, __bf16* __restrict__ wb) {
  int gid = blockIdx.x * 256 + threadIdx.x;
  if (gid >= WB_TOTAL) return;
  const float* srcs[10] = {ew1, ew2, ew3, nw1, nw2, nw3, dw1, dw2, dw3, dw4};
  const float* brow[10] = {eb1, 0, 0, nb1, 0, 0, db1, 0, 0, 0};
  const int Ks[10] = {9, 128, 128, 5, 128, 128, 5, 128, 128, 128};
  const int Ns[10] = {128, 128, 3, 128, 128, 1, 128, 128, 128, 1};
  const int CTs[10] = {8, 8, 1, 8, 8, 1, 8, 8, 8, 1};
  const int cum[11] = {0, 4096, 20480, 22528, 26624, 43008, 45056, 49152, 65536, 81920, 83968};
  int seg = 0;
  while (gid >= cum[seg + 1]) seg++;
  int li = gid - cum[seg];
  int j = li & 7;
  int lane = (li >> 3) & 63;
  int fi = li >> 9;
  int CT = CTs[seg];
  int ct = fi % CT;
  int kt = fi / CT;
  int k = kt * 32 + ((lane >> 4) << 3) + j;
  int n = ct * 16 + (lane & 15);
  float v = 0.f;
  if (n < Ns[seg]) {
    if (k < Ks[seg]) v = srcs[seg][k * Ns[seg] + n];
    else if (brow[seg] && k == Ks[seg]) v = brow[seg][n];
  }
  wb[gid] = (__bf16)v;
}

// ================= init =================
__global__ void k_init_nodes(const float* __restrict__ y_prev, float* __restrict__ x4,
                             float* __restrict__ deg, float* __restrict__ aggr, int n) {
  int i = blockIdx.x * 256 + threadIdx.x;
  if (i < n) {
    x4[i] = y_prev[i];
    deg[i] = 0.f;
    f32x4 z = {0.f, 0.f, 0.f, 0.f};
    *(f32x4*)(aggr + 4 * i) = z;
  }
}

__global__ void k_init_edges(const float* __restrict__ Xc, const float* __restrict__ y_prev,
                             const int* __restrict__ src, const int* __restrict__ dstp,
                             float* __restrict__ pe, float* __restrict__ ea,
                             float* __restrict__ deg, int E) {
  int e = blockIdx.x * 256 + threadIdx.x;
  if (e < E) {
    int s = src[e], d = dstp[e];
    float dx = Xc[d * 6 + 0] - Xc[s * 6 + 0];
    float dy = Xc[d * 6 + 1] - Xc[s * 6 + 1];
    float dz = Xc[d * 6 + 2] - Xc[s * 6 + 2];
    float nr = sqrtf(dx * dx + dy * dy + dz * dz);
    f32x4 p = {dx, dy, dz, nr};
    *(f32x4*)(pe + 4 * e) = p;
    float w = y_prev[d] - y_prev[s];
    f32x4 a = {w * dx, w * dy, w * dz, 0.f};
    *(f32x4*)(ea + 4 * e) = a;
    atomicAdd(deg + d, 1.0f);
  }
}

// ================= MFMA helpers (swapped operands: D = W_frag x act_frag = h^T) =================
// act LDS layout: [16 edge rows][128 h] bf16, row stride 256B, XOR-swizzled byte ^ ((row&7)<<4)
// D-frag: lane l holds edge e=l&15, n = ct*16 + (l>>4)*4 + r

__device__ __forceinline__ void pinv(bf16x8& v) { asm volatile("" : "+v"(v)); }

__device__ __forceinline__ void load_res8(const __bf16* __restrict__ Wf, int lane,
                                          bf16x8 (&wr)[4][8]) {
#pragma unroll
  for (int kt = 0; kt < 4; kt++)
#pragma unroll
    for (int ct = 0; ct < 8; ct++)
      wr[kt][ct] = *(const bf16x8*)(Wf + ((kt * 8 + ct) << 9) + lane * 8);
}

__device__ __forceinline__ bf16x8 read_act(const char* actb, int col, int krow, int kt) {
  int off = (col * 256 + kt * 64 + krow * 16) ^ ((col & 7) << 4);
  return *(const bf16x8*)(actb + off);
}

// relu + stage h^T: lane writes 4 consecutive h of its edge row as one b64
__device__ __forceinline__ void stage_relu_T(char* actb, int col, int krow,
                                             const f32x4 (&acc)[8]) {
#pragma unroll
  for (int ct = 0; ct < 8; ct++) {
    bf16x4 p;
#pragma unroll
    for (int r = 0; r < 4; r++) {
      float v = acc[ct][r];
      p[r] = (__bf16)(v > 0.f ? v : 0.f);
    }
    *(bf16x4*)(actb + ((col * 256 + ct * 32 + krow * 8) ^ ((col & 7) << 4))) = p;
  }
}

// layer1: streams W1 (8 frags) in two pinned halves of 4 (caps live regs at 16)
__device__ __forceinline__ void layer1_gA(const char* actb, int col, int krow, int lane,
                                          const __bf16* __restrict__ W1f, f32x4 (&acc)[8]) {
  bf16x8 b = read_act(actb, col, krow, 0);
  const __bf16* p = W1f;
#pragma unroll
  for (int half = 0; half < 2; half++) {
    asm volatile("" : "+s"(p));
#pragma unroll
    for (int c = 0; c < 4; c++) {
      int ct = half * 4 + c;
      bf16x8 a = *(const bf16x8*)(p + (ct << 9) + lane * 8);
      acc[ct] = __builtin_amdgcn_mfma_f32_16x16x32_bf16(a, b, acc[ct], 0, 0, 0);
    }
  }
}

// layer2: W2 fully register-resident
__device__ __forceinline__ void layer_rB(const char* actb, int col, int krow,
                                         const bf16x8 (&wr)[4][8], f32x4 (&acc)[8]) {
#pragma unroll
  for (int kt = 0; kt < 4; kt++) {
    bf16x8 b = read_act(actb, col, krow, kt);
#pragma unroll
    for (int ct = 0; ct < 8; ct++)
      acc[ct] = __builtin_amdgcn_mfma_f32_16x16x32_bf16(wr[kt][ct], b, acc[ct], 0, 0, 0);
  }
}

// big streamed layer (k_dec layer3): pin per kt caps in-flight at 32 regs
__device__ __forceinline__ void layer_gA(const char* actb, int col, int krow, int lane,
                                         const __bf16* __restrict__ Wf, f32x4 (&acc)[8]) {
  const __bf16* p = Wf;
#pragma unroll
  for (int kt = 0; kt < 4; kt++) {
    asm volatile("" : "+s"(p));
    bf16x8 b = read_act(actb, col, krow, kt);
#pragma unroll
    for (int ct = 0; ct < 8; ct++) {
      bf16x8 a = *(const bf16x8*)(p + ((kt * 8 + ct) << 9) + lane * 8);
      acc[ct] = __builtin_amdgcn_mfma_f32_16x16x32_bf16(a, b, acc[ct], 0, 0, 0);
    }
  }
}

// narrow output layer: streams KT frags (pinned, not hoisted)
template <int KT>
__device__ __forceinline__ f32x4 out_gA(const char* actb, int col, int krow, int lane,
                                        const __bf16* __restrict__ Wf, f32x4 acc) {
  const __bf16* p = Wf;
  asm volatile("" : "+s"(p));
#pragma unroll
  for (int kt = 0; kt < KT; kt++) {
    bf16x8 b = read_act(actb, col, krow, kt);
    bf16x8 a = *(const bf16x8*)(p + (kt << 9) + lane * 8);
    acc = __builtin_amdgcn_mfma_f32_16x16x32_bf16(a, b, acc, 0, 0, 0);
  }
  return acc;
}

// stage the 16x32 input block: lanes<16 write k0..15 (w0,w1), lanes 16..31 zero k16..31
__device__ __forceinline__ void stage_input(char* actb, int l, bf16x8 w0, bf16x8 w1) {
  if (l < 16) {
    int sw = (l & 7) << 4;
    *(bf16x8*)(actb + ((l * 256 + 0) ^ sw)) = w0;
    *(bf16x8*)(actb + ((l * 256 + 16) ^ sw)) = w1;
  } else if (l < 32) {
    int r = l - 16;
    int sw = (r & 7) << 4;
    bf16x8 zz;
#pragma unroll
    for (int q = 0; q < 8; q++) zz[q] = (__bf16)0.f;
    *(bf16x8*)(actb + ((r * 256 + 32) ^ sw)) = zz;
    *(bf16x8*)(actb + ((r * 256 + 48) ^ sw)) = zz;
  }
}

// ================= edge pass =================
struct ED {
  int s, d;
  f32x4 pe4, ea4;
};

__device__ __forceinline__ ED load_ed(int tile, int col, int E, const int* __restrict__ src,
                                      const int* __restrict__ dstp, const float* __restrict__ pe,
                                      const float* __restrict__ ea) {
  int e = tile * 16 + col;
  if (e >= E) e = E - 1;
  ED r;
  r.s = src[e];
  r.d = dstp[e];
  r.pe4 = *(const f32x4*)(pe + 4 * e);
  r.ea4 = *(const f32x4*)(ea + 4 * e);
  return r;
}

__global__ __attribute__((amdgpu_flat_work_group_size(256, 256), amdgpu_waves_per_eu(2, 2))) void
k_edge(const float* __restrict__ x4, const float* __restrict__ pe, float* __restrict__ ea,
       const int* __restrict__ src, const int* __restrict__ dstp, const __bf16* __restrict__ W1f,
       const __bf16* __restrict__ W2f, const __bf16* __restrict__ W3f,
       const float* __restrict__ b2, const float* __restrict__ b3, float* __restrict__ aggr,
       int ntiles, int E) {
  __shared__ char act[4][4096];
  int l = threadIdx.x & 63;
  int widx = threadIdx.x >> 6;
  char* actb = act[widx];
  int col = l & 15, krow = l >> 4;
  int wgid = blockIdx.x * 4 + widx;
  int nw = gridDim.x * 4;

  bf16x8 w2r[4][8];
  load_res8(W2f, l, w2r);
#pragma unroll
  for (int kt = 0; kt < 4; kt++)
#pragma unroll
    for (int ct = 0; ct < 8; ct++) pinv(w2r[kt][ct]);

  f32x4 b3v;
  b3v[0] = b3[0];
  b3v[1] = b3[1];
  b3v[2] = b3[2];
  b3v[3] = 0.f;

  int tile = wgid;
  ED cur;
  float xs4 = 0.f, xd4 = 0.f;
  if (tile < ntiles) {
    cur = load_ed(tile, col, E, src, dstp, pe, ea);
    xs4 = x4[cur.s];
    xd4 = x4[cur.d];
  }

  while (tile < ntiles) {
    int nt = tile + nw;
    ED nxt = cur;
    if (nt < ntiles) nxt = load_ed(nt, col, E, src, dstp, pe, ea);
    float xs4n = x4[nxt.s];
    float xd4n = x4[nxt.d];
    int e0 = tile * 16;

    // stage net_in = [disp(3), norm, ea(3), xs4, xd4, 1(bias)] rows 0..15
    bf16x8 w0, w1;
    w0[0] = (__bf16)cur.pe4[0];
    w0[1] = (__bf16)cur.pe4[1];
    w0[2] = (__bf16)cur.pe4[2];
    w0[3] = (__bf16)cur.pe4[3];
    w0[4] = (__bf16)cur.ea4[0];
    w0[5] = (__bf16)cur.ea4[1];
    w0[6] = (__bf16)cur.ea4[2];
    w0[7] = (__bf16)xs4;
#pragma unroll
    for (int q = 0; q < 8; q++) w1[q] = (__bf16)0.f;
    w1[0] = (__bf16)xd4;
    w1[1] = (__bf16)1.0f;
    stage_input(actb, l, w0, w1);

    // layer 1 (bias folded via 1-slot)
    f32x4 h[8];
#pragma unroll
    for (int ct = 0; ct < 8; ct++) {
      f32x4 z = {0.f, 0.f, 0.f, 0.f};
      h[ct] = z;
    }
    layer1_gA(actb, col, krow, l, W1f, h);
    stage_relu_T(actb, col, krow, h);

    // layer 2 (resident weights, per-tile bias vec loads)
#pragma unroll
    for (int ct = 0; ct < 8; ct++) h[ct] = *(const f32x4*)(b2 + ct * 16 + krow * 4);
    layer_rB(actb, col, krow, w2r, h);
    stage_relu_T(actb, col, krow, h);

    // layer 3 (128 -> 3, streamed W3)
    f32x4 o = out_gA<4>(actb, col, krow, l, W3f, b3v);

    // epilogue: lane e<16 owns edge e: vectorized ea update + 3 atomics
    if (l < 16) {
      int ee = e0 + l;
      if (ee < E) {
        f32x4 nv = cur.ea4;
        nv[0] += o[0];
        nv[1] += o[1];
        nv[2] += o[2];
        *(f32x4*)(ea + 4 * ee) = nv;
        int d4 = cur.d * 4;
        atomicAdd(aggr + d4 + 0, nv[0]);
        atomicAdd(aggr + d4 + 1, nv[1]);
        atomicAdd(aggr + d4 + 2, nv[2]);
      }
    }
    tile = nt;
    cur = nxt;
    xs4 = xs4n;
    xd4 = xd4n;
  }
}

// ================= node pass =================
__global__ __attribute__((amdgpu_flat_work_group_size(256, 256), amdgpu_waves_per_eu(2, 2))) void
k_node(float* __restrict__ x4, const float* __restrict__ Xc, float* __restrict__ aggr,
       const float* __restrict__ deg, const __bf16* __restrict__ W1f,
       const __bf16* __restrict__ W2f, const __bf16* __restrict__ W3f,
       const float* __restrict__ b2, const float* __restrict__ b3, int ntiles, int n) {
  __shared__ char act[4][4096];
  int l = threadIdx.x & 63;
  int widx = threadIdx.x >> 6;
  char* actb = act[widx];
  int col = l & 15, krow = l >> 4;
  int wgid = blockIdx.x * 4 + widx;
  int nw = gridDim.x * 4;

  bf16x8 w2r[4][8];
  load_res8(W2f, l, w2r);
#pragma unroll
  for (int kt = 0; kt < 4; kt++)
#pragma unroll
    for (int ct = 0; ct < 8; ct++) pinv(w2r[kt][ct]);

  float b3s = b3[0];

  for (int tile = wgid; tile < ntiles; tile += nw) {
    int i0 = tile * 16 + col;
    bool vi = i0 < n;
    int i = vi ? i0 : (n - 1);
    float x3 = Xc[i * 6 + 4];
    float xv = x4[i];
    f32x4 ag = *(const f32x4*)(aggr + 4 * i);
    float dg = deg[i];
    float inv = dg > 0.f ? 1.0f / dg : 0.f;

    if (l < 16 && vi) {
      f32x4 z = {0.f, 0.f, 0.f, 0.f};
      *(f32x4*)(aggr + 4 * i) = z;  // clear for next iteration
    }

    bf16x8 w0, w1;
#pragma unroll
    for (int q = 0; q < 8; q++) w1[q] = (__bf16)0.f;
    w0 = w1;
    w0[0] = (__bf16)x3;
    w0[1] = (__bf16)xv;
    w0[2] = (__bf16)(ag[0] * inv);
    w0[3] = (__bf16)(ag[1] * inv);
    w0[4] = (__bf16)(ag[2] * inv);
    w0[5] = (__bf16)1.0f;
    stage_input(actb, l, w0, w1);

    f32x4 h[8];
#pragma unroll
    for (int ct = 0; ct < 8; ct++) {
      f32x4 z = {0.f, 0.f, 0.f, 0.f};
      h[ct] = z;
    }
    layer1_gA(actb, col, krow, l, W1f, h);
    stage_relu_T(actb, col, krow, h);

#pragma unroll
    for (int ct = 0; ct < 8; ct++) h[ct] = *(const f32x4*)(b2 + ct * 16 + krow * 4);
    layer_rB(actb, col, krow, w2r, h);
    stage_relu_T(actb, col, krow, h);

    f32x4 ob;
    ob[0] = ob[1] = ob[2] = ob[3] = b3s;
    f32x4 o = out_gA<4>(actb, col, krow, l, W3f, ob);

    if (l < 16 && vi) x4[i0] = xv + o[0];
  }
}

// ================= decoder =================
__global__ __attribute__((amdgpu_flat_work_group_size(256, 256), amdgpu_waves_per_eu(2, 2))) void
k_dec(const float* __restrict__ x4, const float* __restrict__ Xc, const float* __restrict__ y_prev,
      const __bf16* __restrict__ W1f, const __bf16* __restrict__ W2f,
      const __bf16* __restrict__ W3f, const __bf16* __restrict__ W4f,
      const float* __restrict__ b2, const float* __restrict__ b3, const float* __restrict__ b4,
      float* __restrict__ out, int ntiles, int n) {
  __shared__ char act[4][4096];
  int l = threadIdx.x & 63;
  int widx = threadIdx.x >> 6;
  char* actb = act[widx];
  int col = l & 15, krow = l >> 4;
  int wgid = blockIdx.x * 4 + widx;
  int nw = gridDim.x * 4;

  bf16x8 w2r[4][8];
  load_res8(W2f, l, w2r);
#pragma unroll
  for (int kt = 0; kt < 4; kt++)
#pragma unroll
    for (int ct = 0; ct < 8; ct++) pinv(w2r[kt][ct]);

  float b4s = b4[0];

  for (int tile = wgid; tile < ntiles; tile += nw) {
    int i0 = tile * 16 + col;
    bool vi = i0 < n;
    int i = vi ? i0 : (n - 1);

    bf16x8 w0, w1;
#pragma unroll
    for (int q = 0; q < 8; q++) w1[q] = (__bf16)0.f;
    w0 = w1;
    w0[0] = (__bf16)Xc[i * 6 + 0];
    w0[1] = (__bf16)Xc[i * 6 + 1];
    w0[2] = (__bf16)Xc[i * 6 + 2];
    w0[3] = (__bf16)Xc[i * 6 + 4];
    w0[4] = (__bf16)x4[i];
    w0[5] = (__bf16)1.0f;
    stage_input(actb, l, w0, w1);

    f32x4 h[8];
#pragma unroll
    for (int ct = 0; ct < 8; ct++) {
      f32x4 z = {0.f, 0.f, 0.f, 0.f};
      h[ct] = z;
    }
    layer1_gA(actb, col, krow, l, W1f, h);
    stage_relu_T(actb, col, krow, h);

#pragma unroll
    for (int ct = 0; ct < 8; ct++) h[ct] = *(const f32x4*)(b2 + ct * 16 + krow * 4);
    layer_rB(actb, col, krow, w2r, h);
    stage_relu_T(actb, col, krow, h);

#pragma unroll
    for (int ct = 0; ct < 8; ct++) h[ct] = *(const f32x4*)(b3 + ct * 16 + krow * 4);
    layer_gA(actb, col, krow, l, W3f, h);
    stage_relu_T(actb, col, krow, h);

    f32x4 ob;
    ob[0] = ob[1] = ob[2] = ob[3] = b4s;
    f32x4 o = out_gA<4>(actb, col, krow, l, W4f, ob);

    if (l < 16 && vi) out[i0] = y_prev[i0] + o[0];
  }
}

// ================= host =================
extern "C" void kernel_launch(void* const* d_in, const int* in_sizes, int n_in, void* d_out,
                              int out_size, void* d_ws, size_t ws_size, hipStream_t stream) {
  const float* Xc = (const float*)d_in[0];
  const float* y_prev = (const float*)d_in[1];
  const int* edge = (const int*)d_in[2];
  const float* ew1 = (const float*)d_in[4];
  const float* eb1 = (const float*)d_in[5];
  const float* ew2 = (const float*)d_in[6];
  const float* eb2 = (const float*)d_in[7];
  const float* ew3 = (const float*)d_in[8];
  const float* eb3 = (const float*)d_in[9];
  const float* nw1 = (const float*)d_in[10];
  const float* nb1 = (const float*)d_in[11];
  const float* nw2 = (const float*)d_in[12];
  const float* nb2 = (const float*)d_in[13];
  const float* nw3 = (const float*)d_in[14];
  const float* nb3 = (const float*)d_in[15];
  const float* dw1 = (const float*)d_in[16];
  const float* db1 = (const float*)d_in[17];
  const float* dw2 = (const float*)d_in[18];
  const float* db2 = (const float*)d_in[19];
  const float* dw3 = (const float*)d_in[20];
  const float* db3 = (const float*)d_in[21];
  const float* dw4 = (const float*)d_in[22];
  const float* db4 = (const float*)d_in[23];

  int n = in_sizes[0] / 6;
  int E = in_sizes[2] / 2;
  const int* srcp = edge;
  const int* dstp = edge + E;

  __bf16* wb = (__bf16*)d_ws;
  float* fbase = (float*)((char*)d_ws + (size_t)WB_TOTAL * 2);
  size_t na = ((size_t)n + 3) & ~(size_t)3;
  float* x4 = fbase;
  float* deg = fbase + na;
  float* aggr = fbase + 2 * na;
  float* pe = fbase + 6 * na;
  float* ea = fbase + 6 * na + 4 * (size_t)E;

  size_t need = (size_t)WB_TOTAL * 2 + (6 * na + 8 * (size_t)E) * 4;
  if (ws_size < need) return;

  dim3 B(256);
  k_prep<<<dim3((WB_TOTAL + 255) / 256), B, 0, stream>>>(ew1, eb1, ew2, ew3, nw1, nb1, nw2, nw3,
                                                         dw1, db1, dw2, dw3, dw4, wb);
  k_init_nodes<<<dim3((n + 255) / 256), B, 0, stream>>>(y_prev, x4, deg, aggr, n);
  k_init_edges<<<dim3((E + 255) / 256), B, 0, stream>>>(Xc, y_prev, srcp, dstp, pe, ea, deg, E);

  int etiles = (E + 15) / 16;
  int vtiles = (n + 15) / 16;
  for (int it = 0; it < 3; it++) {
    k_edge<<<dim3(512), B, 0, stream>>>(x4, pe, ea, srcp, dstp, wb + WB_W1E, wb + WB_W2E,
                                        wb + WB_W3E, eb2, eb3, aggr, etiles, E);
    k_node<<<dim3(512), B, 0, stream>>>(x4, Xc, aggr, deg, wb + WB_W1N, wb + WB_W2N, wb + WB_W3N,
                                        nb2, nb3, vtiles, n);
  }
  k_dec<<<dim3(512), B, 0, stream>>>(x4, Xc, y_prev, wb + WB_W1D, wb + WB_W2D, wb + WB_W3D,
                                     wb + WB_W4D, db2, db3, db4, (float*)d_out, vtiles, n);
}

// Round 4
// 481.825 us; speedup vs baseline: 1.1932x; 1.0464x over previous
//
#include <hip/hip_runtime.h>

typedef float f32x4 __attribute__((ext_vector_type(4)));
typedef __bf16 bf16x8 __attribute__((ext_vector_type(8)));
typedef __bf16 bf16x4 __attribute__((ext_vector_type(4)));

// ---- workspace layout: bf16 weight-fragment region, then f32 region ----
#define WB_W1E 0
#define WB_W2E 4096
#define WB_W3E 20480
#define WB_W1N 22528
#define WB_W2N 26624
#define WB_W3N 43008
#define WB_W1D 45056
#define WB_W2D 49152
#define WB_W3D 65536
#define WB_W4D 81920
#define WB_TOTAL 83968

// ================= weight prep: f32 row-major [K][N] -> fragmented bf16 =================
// frag fi = kt*CT+ct, within frag lane-major 8 elems:
//   value = W[klogical][ct*16 + (lane&15)], physical k = kt*32 + (lane>>4)*8 + j
// Physical-k layout is chosen to match chunked input staging:
//  seg0 (ew1):  p0..3 = disp/norm, p8..10 = ea, p11 = xs, p12 = xd, p13 = bias
//  seg3/6 (nw1/dw1): p0..4 = inputs, p5 = bias
__global__ void k_prep(const float* __restrict__ ew1, const float* __restrict__ eb1,
                       const float* __restrict__ ew2, const float* __restrict__ ew3,
                       const float* __restrict__ nw1, const float* __restrict__ nb1,
                       const float* __restrict__ nw2, const float* __restrict__ nw3,
                       const float* __restrict__ dw1, const float* __restrict__ db1,
                       const float* __restrict__ dw2, const float* __restrict__ dw3,
                       const float* __restrict__ dw4, __bf16* __restrict__ wb) {
  int gid = blockIdx.x * 256 + threadIdx.x;
  if (gid >= WB_TOTAL) return;
  const float* srcs[10] = {ew1, ew2, ew3, nw1, nw2, nw3, dw1, dw2, dw3, dw4};
  const float* brow[10] = {eb1, 0, 0, nb1, 0, 0, db1, 0, 0, 0};
  const int Ks[10] = {9, 128, 128, 5, 128, 128, 5, 128, 128, 128};
  const int Ns[10] = {128, 128, 3, 128, 128, 1, 128, 128, 128, 1};
  const int CTs[10] = {8, 8, 1, 8, 8, 1, 8, 8, 8, 1};
  const int cum[11] = {0, 4096, 20480, 22528, 26624, 43008, 45056, 49152, 65536, 81920, 83968};
  int seg = 0;
  while (gid >= cum[seg + 1]) seg++;
  int li = gid - cum[seg];
  int j = li & 7;
  int lane = (li >> 3) & 63;
  int fi = li >> 9;
  int CT = CTs[seg];
  int ct = fi % CT;
  int kt = fi / CT;
  int k = kt * 32 + ((lane >> 4) << 3) + j;  // physical k
  int n = ct * 16 + (lane & 15);
  int kl;  // logical row; -1 = zero, -2 = bias
  if (seg == 0) {
    if (k < 4) kl = k;
    else if (k >= 8 && k < 13) kl = k - 4;
    else kl = (k == 13) ? -2 : -1;
  } else if (seg == 3 || seg == 6) {
    if (k < 5) kl = k;
    else kl = (k == 5) ? -2 : -1;
  } else {
    kl = (k < Ks[seg]) ? k : -1;
  }
  float v = 0.f;
  if (n < Ns[seg]) {
    if (kl >= 0) v = srcs[seg][kl * Ns[seg] + n];
    else if (kl == -2 && brow[seg]) v = brow[seg][n];
  }
  wb[gid] = (__bf16)v;
}

// ================= init =================
__global__ void k_init_nodes(const float* __restrict__ y_prev, float* __restrict__ x4,
                             float* __restrict__ deg, float* __restrict__ aggr, int n) {
  int i = blockIdx.x * 256 + threadIdx.x;
  if (i < n) {
    x4[i] = y_prev[i];
    deg[i] = 0.f;
    f32x4 z = {0.f, 0.f, 0.f, 0.f};
    *(f32x4*)(aggr + 4 * i) = z;
  }
}

__global__ void k_init_edges(const float* __restrict__ Xc, const float* __restrict__ y_prev,
                             const int* __restrict__ src, const int* __restrict__ dstp,
                             float* __restrict__ pe, float* __restrict__ ea,
                             float* __restrict__ deg, int E) {
  int e = blockIdx.x * 256 + threadIdx.x;
  if (e < E) {
    int s = src[e], d = dstp[e];
    float dx = Xc[d * 6 + 0] - Xc[s * 6 + 0];
    float dy = Xc[d * 6 + 1] - Xc[s * 6 + 1];
    float dz = Xc[d * 6 + 2] - Xc[s * 6 + 2];
    float nr = sqrtf(dx * dx + dy * dy + dz * dz);
    f32x4 p = {dx, dy, dz, nr};
    *(f32x4*)(pe + 4 * e) = p;
    float w = y_prev[d] - y_prev[s];
    f32x4 a = {w * dx, w * dy, w * dz, 0.f};
    *(f32x4*)(ea + 4 * e) = a;
    atomicAdd(deg + d, 1.0f);
  }
}

// ================= shared helpers =================
// act LDS: [64 rows][128 h] bf16, 256B row stride, XOR swizzle byte ^ ((row&7)<<4)
__device__ __forceinline__ int aoff(int row, int b) { return (row * 256 + b) ^ ((row & 7) << 4); }

// raw barrier: make LDS writes visible WITHOUT draining vmcnt (keeps prefetch in flight)
__device__ __forceinline__ void wg_sync() {
  asm volatile("s_waitcnt lgkmcnt(0)" ::: "memory");
  __builtin_amdgcn_s_barrier();
}

__device__ __forceinline__ bf16x4 relu_pack(f32x4 a) {
  bf16x4 p;
#pragma unroll
  for (int r = 0; r < 4; r++) {
    float v = a[r];
    p[r] = (__bf16)(v > 0.f ? v : 0.f);
  }
  return p;
}

// ================= edge pass: 4-wave WG, 64 edges/tile, n-sliced layers =================
__global__ __attribute__((amdgpu_flat_work_group_size(256, 256), amdgpu_waves_per_eu(3, 4))) void
k_edge(const float* __restrict__ x4, const float* __restrict__ pe, float* __restrict__ ea,
       const int* __restrict__ src, const int* __restrict__ dstp,
       const __bf16* __restrict__ W1f, const __bf16* __restrict__ W2f,
       const __bf16* __restrict__ W3f, const float* __restrict__ b2,
       const float* __restrict__ b3, float* __restrict__ aggr, int ntiles, int E) {
  __shared__ char Ab[16384];
  __shared__ char Bb[16384];
  const int tid = threadIdx.x;
  const int l = tid & 63, w = tid >> 6;
  const int col = l & 15, krow = l >> 4;
  const int rl = w * 16 + (l >> 2), chunk = l & 3;  // staging row + 16B chunk

  // resident weight slices: wave w owns output cols n in [w*32, w*32+32)
  bf16x8 w1r[2], w2r[4][2], w3r[4];
#pragma unroll
  for (int t = 0; t < 2; t++) w1r[t] = *(const bf16x8*)(W1f + ((2 * w + t) << 9) + l * 8);
#pragma unroll
  for (int kt = 0; kt < 4; kt++)
#pragma unroll
    for (int t = 0; t < 2; t++)
      w2r[kt][t] = *(const bf16x8*)(W2f + ((kt * 8 + 2 * w + t) << 9) + l * 8);
#pragma unroll
  for (int kt = 0; kt < 4; kt++) w3r[kt] = *(const bf16x8*)(W3f + (kt << 9) + l * 8);
  f32x4 b2c[2];
#pragma unroll
  for (int t = 0; t < 2; t++) b2c[t] = *(const f32x4*)(b2 + (2 * w + t) * 16 + krow * 4);
  f32x4 b3i = {0.f, 0.f, 0.f, 0.f};
  if (krow == 0) {
    b3i[0] = b3[0];
    b3i[1] = b3[1];
    b3i[2] = b3[2];
  }

  int tile = blockIdx.x;
  if (tile >= ntiles) return;

  // prologue: load current tile's edge data (per-lane row rl, chunk role)
  int e0 = tile * 64 + rl;
  int cs = src[e0], cd = dstp[e0];
  f32x4 cld = {0.f, 0.f, 0.f, 0.f};
  if (chunk < 2) cld = *(const f32x4*)(((chunk == 1) ? ea : pe) + 4 * e0);
  float cxs = 0.f, cxd = 0.f;
  if (chunk == 1) {
    cxs = x4[cs];
    cxd = x4[cd];
  }

  for (;;) {
    // ---- stage input: chunk0=[disp,norm,0..], chunk1=[ea,xs,xd,1,0,0], chunk2/3=0 ----
    bf16x8 v;
#pragma unroll
    for (int q = 0; q < 8; q++) v[q] = (__bf16)0.f;
    if (chunk == 0) {
      v[0] = (__bf16)cld[0];
      v[1] = (__bf16)cld[1];
      v[2] = (__bf16)cld[2];
      v[3] = (__bf16)cld[3];
    } else if (chunk == 1) {
      v[0] = (__bf16)cld[0];
      v[1] = (__bf16)cld[1];
      v[2] = (__bf16)cld[2];
      v[3] = (__bf16)cxs;
      v[4] = (__bf16)cxd;
      v[5] = (__bf16)1.0f;
    }
    *(bf16x8*)(Ab + aoff(rl, chunk * 16)) = v;

    // prefetch stage A: next tile's indices
    int nt = tile + (int)gridDim.x;
    bool hn = nt < ntiles;
    int tc = hn ? nt : tile;
    int en = tc * 64 + rl;
    int ns = src[en], nd = dstp[en];

    wg_sync();  // A ready (input)

    // ---- layer1 (K=32, bias folded via 1-slot) ----
    f32x4 h[4][2];
#pragma unroll
    for (int c = 0; c < 4; c++)
#pragma unroll
      for (int t = 0; t < 2; t++) {
        f32x4 z = {0.f, 0.f, 0.f, 0.f};
        h[c][t] = z;
      }
    bf16x8 bb[4];
#pragma unroll
    for (int c = 0; c < 4; c++) bb[c] = *(const bf16x8*)(Ab + aoff(c * 16 + col, krow * 16));
#pragma unroll
    for (int c = 0; c < 4; c++)
#pragma unroll
      for (int t = 0; t < 2; t++)
        h[c][t] = __builtin_amdgcn_mfma_f32_16x16x32_bf16(w1r[t], bb[c], h[c][t], 0, 0, 0);
#pragma unroll
    for (int c = 0; c < 4; c++)
#pragma unroll
      for (int t = 0; t < 2; t++)
        *(bf16x4*)(Bb + aoff(c * 16 + col, (2 * w + t) * 32 + krow * 8)) = relu_pack(h[c][t]);

    wg_sync();  // B ready (h1)

    // prefetch stage B: dependent gathers (ns/nd arrived by now)
    f32x4 nld = {0.f, 0.f, 0.f, 0.f};
    if (chunk < 2) nld = *(const f32x4*)(((chunk == 1) ? ea : pe) + 4 * en);
    float nxs = 0.f, nxd = 0.f;
    if (chunk == 1) {
      nxs = x4[ns];
      nxd = x4[nd];
    }

    // ---- layer2 (128x128, resident slice) ----
#pragma unroll
    for (int c = 0; c < 4; c++)
#pragma unroll
      for (int t = 0; t < 2; t++) h[c][t] = b2c[t];
#pragma unroll
    for (int kt = 0; kt < 4; kt++) {
#pragma unroll
      for (int c = 0; c < 4; c++)
        bb[c] = *(const bf16x8*)(Bb + aoff(c * 16 + col, kt * 64 + krow * 16));
#pragma unroll
      for (int c = 0; c < 4; c++)
#pragma unroll
        for (int t = 0; t < 2; t++)
          h[c][t] = __builtin_amdgcn_mfma_f32_16x16x32_bf16(w2r[kt][t], bb[c], h[c][t], 0, 0, 0);
    }
#pragma unroll
    for (int c = 0; c < 4; c++)
#pragma unroll
      for (int t = 0; t < 2; t++)
        *(bf16x4*)(Ab + aoff(c * 16 + col, (2 * w + t) * 32 + krow * 8)) = relu_pack(h[c][t]);

    wg_sync();  // A ready (h2)

    // ---- layer3 (128 -> 3): wave w handles its own 16 edges ----
    f32x4 o = b3i;
#pragma unroll
    for (int kt = 0; kt < 4; kt++) {
      bf16x8 bq = *(const bf16x8*)(Ab + aoff(w * 16 + col, kt * 64 + krow * 16));
      o = __builtin_amdgcn_mfma_f32_16x16x32_bf16(w3r[kt], bq, o, 0, 0, 0);
    }

    // ---- epilogue: krow0 lane col owns edge e3; ea RMW + 3 atomics ----
    if (krow == 0) {
      int e3 = tile * 64 + w * 16 + col;
      if (e3 < E) {
        f32x4 oe = *(const f32x4*)(ea + 4 * e3);
        f32x4 nv;
        nv[0] = oe[0] + o[0];
        nv[1] = oe[1] + o[1];
        nv[2] = oe[2] + o[2];
        nv[3] = 0.f;
        *(f32x4*)(ea + 4 * e3) = nv;
        int dd = dstp[e3];
        atomicAdd(aggr + dd * 4 + 0, nv[0]);
        atomicAdd(aggr + dd * 4 + 1, nv[1]);
        atomicAdd(aggr + dd * 4 + 2, nv[2]);
      }
    }

    if (!hn) break;
    tile = nt;
    cld = nld;
    cxs = nxs;
    cxd = nxd;
  }
}

// ================= node pass: one 64-node tile per WG =================
__global__ __attribute__((amdgpu_flat_work_group_size(256, 256), amdgpu_waves_per_eu(3, 4))) void
k_node(float* __restrict__ x4, const float* __restrict__ Xc, float* __restrict__ aggr,
       const float* __restrict__ deg, const __bf16* __restrict__ W1f,
       const __bf16* __restrict__ W2f, const __bf16* __restrict__ W3f,
       const float* __restrict__ b2, const float* __restrict__ b3, int n) {
  __shared__ char Ab[16384];
  __shared__ char Bb[16384];
  const int tid = threadIdx.x;
  const int l = tid & 63, w = tid >> 6;
  const int col = l & 15, krow = l >> 4;
  const int rl = w * 16 + (l >> 2), chunk = l & 3;

  bf16x8 w1r[2], w2r[4][2], w3r[4];
#pragma unroll
  for (int t = 0; t < 2; t++) w1r[t] = *(const bf16x8*)(W1f + ((2 * w + t) << 9) + l * 8);
#pragma unroll
  for (int kt = 0; kt < 4; kt++)
#pragma unroll
    for (int t = 0; t < 2; t++)
      w2r[kt][t] = *(const bf16x8*)(W2f + ((kt * 8 + 2 * w + t) << 9) + l * 8);
#pragma unroll
  for (int kt = 0; kt < 4; kt++) w3r[kt] = *(const bf16x8*)(W3f + (kt << 9) + l * 8);
  f32x4 b2c[2];
#pragma unroll
  for (int t = 0; t < 2; t++) b2c[t] = *(const f32x4*)(b2 + (2 * w + t) * 16 + krow * 4);
  float b3s = b3[0];

  int tile = blockIdx.x;
  int i0 = tile * 64 + rl;
  bool vi = i0 < n;
  int i = vi ? i0 : (n - 1);

  bf16x8 v;
#pragma unroll
  for (int q = 0; q < 8; q++) v[q] = (__bf16)0.f;
  if (chunk == 0) {
    float x3 = Xc[i * 6 + 4];
    float xv = x4[i];
    f32x4 ag = *(const f32x4*)(aggr + 4 * i);
    float dg = deg[i];
    float inv = dg > 0.f ? 1.0f / dg : 0.f;
    v[0] = (__bf16)x3;
    v[1] = (__bf16)xv;
    v[2] = (__bf16)(ag[0] * inv);
    v[3] = (__bf16)(ag[1] * inv);
    v[4] = (__bf16)(ag[2] * inv);
    v[5] = (__bf16)1.0f;
    if (vi) {
      f32x4 z = {0.f, 0.f, 0.f, 0.f};
      *(f32x4*)(aggr + 4 * i) = z;  // clear for next iteration
    }
  }
  *(bf16x8*)(Ab + aoff(rl, chunk * 16)) = v;

  wg_sync();

  f32x4 h[4][2];
#pragma unroll
  for (int c = 0; c < 4; c++)
#pragma unroll
    for (int t = 0; t < 2; t++) {
      f32x4 z = {0.f, 0.f, 0.f, 0.f};
      h[c][t] = z;
    }
  bf16x8 bb[4];
#pragma unroll
  for (int c = 0; c < 4; c++) bb[c] = *(const bf16x8*)(Ab + aoff(c * 16 + col, krow * 16));
#pragma unroll
  for (int c = 0; c < 4; c++)
#pragma unroll
    for (int t = 0; t < 2; t++)
      h[c][t] = __builtin_amdgcn_mfma_f32_16x16x32_bf16(w1r[t], bb[c], h[c][t], 0, 0, 0);
#pragma unroll
  for (int c = 0; c < 4; c++)
#pragma unroll
    for (int t = 0; t < 2; t++)
      *(bf16x4*)(Bb + aoff(c * 16 + col, (2 * w + t) * 32 + krow * 8)) = relu_pack(h[c][t]);

  wg_sync();

#pragma unroll
  for (int c = 0; c < 4; c++)
#pragma unroll
    for (int t = 0; t < 2; t++) h[c][t] = b2c[t];
#pragma unroll
  for (int kt = 0; kt < 4; kt++) {
#pragma unroll
    for (int c = 0; c < 4; c++)
      bb[c] = *(const bf16x8*)(Bb + aoff(c * 16 + col, kt * 64 + krow * 16));
#pragma unroll
    for (int c = 0; c < 4; c++)
#pragma unroll
      for (int t = 0; t < 2; t++)
        h[c][t] = __builtin_amdgcn_mfma_f32_16x16x32_bf16(w2r[kt][t], bb[c], h[c][t], 0, 0, 0);
  }
#pragma unroll
  for (int c = 0; c < 4; c++)
#pragma unroll
    for (int t = 0; t < 2; t++)
      *(bf16x4*)(Ab + aoff(c * 16 + col, (2 * w + t) * 32 + krow * 8)) = relu_pack(h[c][t]);

  wg_sync();

  f32x4 o = {0.f, 0.f, 0.f, 0.f};
  if (krow == 0) o[0] = b3s;
#pragma unroll
  for (int kt = 0; kt < 4; kt++) {
    bf16x8 bq = *(const bf16x8*)(Ab + aoff(w * 16 + col, kt * 64 + krow * 16));
    o = __builtin_amdgcn_mfma_f32_16x16x32_bf16(w3r[kt], bq, o, 0, 0, 0);
  }

  if (krow == 0) {
    int i3 = tile * 64 + w * 16 + col;
    if (i3 < n) x4[i3] = x4[i3] + o[0];
  }
}

// ================= decoder: one 64-node tile per WG, 4 layers =================
__global__ __attribute__((amdgpu_flat_work_group_size(256, 256), amdgpu_waves_per_eu(2, 4))) void
k_dec(const float* __restrict__ x4, const float* __restrict__ Xc, const float* __restrict__ y_prev,
      const __bf16* __restrict__ W1f, const __bf16* __restrict__ W2f,
      const __bf16* __restrict__ W3f, const __bf16* __restrict__ W4f,
      const float* __restrict__ b2, const float* __restrict__ b3, const float* __restrict__ b4,
      float* __restrict__ out, int n) {
  __shared__ char Ab[16384];
  __shared__ char Bb[16384];
  const int tid = threadIdx.x;
  const int l = tid & 63, w = tid >> 6;
  const int col = l & 15, krow = l >> 4;
  const int rl = w * 16 + (l >> 2), chunk = l & 3;

  bf16x8 w1r[2], w2r[4][2], w3r[4][2], w4r[4];
#pragma unroll
  for (int t = 0; t < 2; t++) w1r[t] = *(const bf16x8*)(W1f + ((2 * w + t) << 9) + l * 8);
#pragma unroll
  for (int kt = 0; kt < 4; kt++)
#pragma unroll
    for (int t = 0; t < 2; t++) {
      w2r[kt][t] = *(const bf16x8*)(W2f + ((kt * 8 + 2 * w + t) << 9) + l * 8);
      w3r[kt][t] = *(const bf16x8*)(W3f + ((kt * 8 + 2 * w + t) << 9) + l * 8);
    }
#pragma unroll
  for (int kt = 0; kt < 4; kt++) w4r[kt] = *(const bf16x8*)(W4f + (kt << 9) + l * 8);
  f32x4 b2c[2], b3c[2];
#pragma unroll
  for (int t = 0; t < 2; t++) {
    b2c[t] = *(const f32x4*)(b2 + (2 * w + t) * 16 + krow * 4);
    b3c[t] = *(const f32x4*)(b3 + (2 * w + t) * 16 + krow * 4);
  }
  float b4s = b4[0];

  int tile = blockIdx.x;
  int i0 = tile * 64 + rl;
  bool vi = i0 < n;
  int i = vi ? i0 : (n - 1);

  bf16x8 v;
#pragma unroll
  for (int q = 0; q < 8; q++) v[q] = (__bf16)0.f;
  if (chunk == 0) {
    v[0] = (__bf16)Xc[i * 6 + 0];
    v[1] = (__bf16)Xc[i * 6 + 1];
    v[2] = (__bf16)Xc[i * 6 + 2];
    v[3] = (__bf16)Xc[i * 6 + 4];
    v[4] = (__bf16)x4[i];
    v[5] = (__bf16)1.0f;
  }
  *(bf16x8*)(Ab + aoff(rl, chunk * 16)) = v;

  wg_sync();

  f32x4 h[4][2];
  bf16x8 bb[4];
  // layer1 -> B
#pragma unroll
  for (int c = 0; c < 4; c++)
#pragma unroll
    for (int t = 0; t < 2; t++) {
      f32x4 z = {0.f, 0.f, 0.f, 0.f};
      h[c][t] = z;
    }
#pragma unroll
  for (int c = 0; c < 4; c++) bb[c] = *(const bf16x8*)(Ab + aoff(c * 16 + col, krow * 16));
#pragma unroll
  for (int c = 0; c < 4; c++)
#pragma unroll
    for (int t = 0; t < 2; t++)
      h[c][t] = __builtin_amdgcn_mfma_f32_16x16x32_bf16(w1r[t], bb[c], h[c][t], 0, 0, 0);
#pragma unroll
  for (int c = 0; c < 4; c++)
#pragma unroll
    for (int t = 0; t < 2; t++)
      *(bf16x4*)(Bb + aoff(c * 16 + col, (2 * w + t) * 32 + krow * 8)) = relu_pack(h[c][t]);

  wg_sync();

  // layer2 -> A
#pragma unroll
  for (int c = 0; c < 4; c++)
#pragma unroll
    for (int t = 0; t < 2; t++) h[c][t] = b2c[t];
#pragma unroll
  for (int kt = 0; kt < 4; kt++) {
#pragma unroll
    for (int c = 0; c < 4; c++)
      bb[c] = *(const bf16x8*)(Bb + aoff(c * 16 + col, kt * 64 + krow * 16));
#pragma unroll
    for (int c = 0; c < 4; c++)
#pragma unroll
      for (int t = 0; t < 2; t++)
        h[c][t] = __builtin_amdgcn_mfma_f32_16x16x32_bf16(w2r[kt][t], bb[c], h[c][t], 0, 0, 0);
  }
#pragma unroll
  for (int c = 0; c < 4; c++)
#pragma unroll
    for (int t = 0; t < 2; t++)
      *(bf16x4*)(Ab + aoff(c * 16 + col, (2 * w + t) * 32 + krow * 8)) = relu_pack(h[c][t]);

  wg_sync();

  // layer3 -> B
#pragma unroll
  for (int c = 0; c < 4; c++)
#pragma unroll
    for (int t = 0; t < 2; t++) h[c][t] = b3c[t];
#pragma unroll
  for (int kt = 0; kt < 4; kt++) {
#pragma unroll
    for (int c = 0; c < 4; c++)
      bb[c] = *(const bf16x8*)(Ab + aoff(c * 16 + col, kt * 64 + krow * 16));
#pragma unroll
    for (int c = 0; c < 4; c++)
#pragma unroll
      for (int t = 0; t < 2; t++)
        h[c][t] = __builtin_amdgcn_mfma_f32_16x16x32_bf16(w3r[kt][t], bb[c], h[c][t], 0, 0, 0);
  }
#pragma unroll
  for (int c = 0; c < 4; c++)
#pragma unroll
    for (int t = 0; t < 2; t++)
      *(bf16x4*)(Bb + aoff(c * 16 + col, (2 * w + t) * 32 + krow * 8)) = relu_pack(h[c][t]);

  wg_sync();

  // layer4 (128 -> 1)
  f32x4 o = {0.f, 0.f, 0.f, 0.f};
  if (krow == 0) o[0] = b4s;
#pragma unroll
  for (int kt = 0; kt < 4; kt++) {
    bf16x8 bq = *(const bf16x8*)(Bb + aoff(w * 16 + col, kt * 64 + krow * 16));
    o = __builtin_amdgcn_mfma_f32_16x16x32_bf16(w4r[kt], bq, o, 0, 0, 0);
  }

  if (krow == 0) {
    int i3 = tile * 64 + w * 16 + col;
    if (i3 < n) out[i3] = y_prev[i3] + o[0];
  }
}

// ================= host =================
extern "C" void kernel_launch(void* const* d_in, const int* in_sizes, int n_in, void* d_out,
                              int out_size, void* d_ws, size_t ws_size, hipStream_t stream) {
  const float* Xc = (const float*)d_in[0];
  const float* y_prev = (const float*)d_in[1];
  const int* edge = (const int*)d_in[2];
  const float* ew1 = (const float*)d_in[4];
  const float* eb1 = (const float*)d_in[5];
  const float* ew2 = (const float*)d_in[6];
  const float* eb2 = (const float*)d_in[7];
  const float* ew3 = (const float*)d_in[8];
  const float* eb3 = (const float*)d_in[9];
  const float* nw1 = (const float*)d_in[10];
  const float* nb1 = (const float*)d_in[11];
  const float* nw2 = (const float*)d_in[12];
  const float* nb2 = (const float*)d_in[13];
  const float* nw3 = (const float*)d_in[14];
  const float* nb3 = (const float*)d_in[15];
  const float* dw1 = (const float*)d_in[16];
  const float* db1 = (const float*)d_in[17];
  const float* dw2 = (const float*)d_in[18];
  const float* db2 = (const float*)d_in[19];
  const float* dw3 = (const float*)d_in[20];
  const float* db3 = (const float*)d_in[21];
  const float* dw4 = (const float*)d_in[22];
  const float* db4 = (const float*)d_in[23];

  int n = in_sizes[0] / 6;
  int E = in_sizes[2] / 2;
  const int* srcp = edge;
  const int* dstp = edge + E;

  __bf16* wb = (__bf16*)d_ws;
  float* fbase = (float*)((char*)d_ws + (size_t)WB_TOTAL * 2);
  size_t na = ((size_t)n + 3) & ~(size_t)3;
  float* x4 = fbase;
  float* deg = fbase + na;
  float* aggr = fbase + 2 * na;
  float* pe = fbase + 6 * na;
  float* ea = fbase + 6 * na + 4 * (size_t)E;

  size_t need = (size_t)WB_TOTAL * 2 + (6 * na + 8 * (size_t)E) * 4;
  if (ws_size < need) return;

  dim3 B(256);
  k_prep<<<dim3((WB_TOTAL + 255) / 256), B, 0, stream>>>(ew1, eb1, ew2, ew3, nw1, nb1, nw2, nw3,
                                                         dw1, db1, dw2, dw3, dw4, wb);
  k_init_nodes<<<dim3((n + 255) / 256), B, 0, stream>>>(y_prev, x4, deg, aggr, n);
  k_init_edges<<<dim3((E + 255) / 256), B, 0, stream>>>(Xc, y_prev, srcp, dstp, pe, ea, deg, E);

  int etiles = (E + 63) / 64;
  int vtiles = (n + 63) / 64;
  int egrid = etiles < 768 ? etiles : 768;
  for (int it = 0; it < 3; it++) {
    k_edge<<<dim3(egrid), B, 0, stream>>>(x4, pe, ea, srcp, dstp, wb + WB_W1E, wb + WB_W2E,
                                          wb + WB_W3E, eb2, eb3, aggr, etiles, E);
    k_node<<<dim3(vtiles), B, 0, stream>>>(x4, Xc, aggr, deg, wb + WB_W1N, wb + WB_W2N,
                                           wb + WB_W3N, nb2, nb3, n);
  }
  k_dec<<<dim3(vtiles), B, 0, stream>>>(x4, Xc, y_prev, wb + WB_W1D, wb + WB_W2D, wb + WB_W3D,
                                        wb + WB_W4D, db2, db3, db4, (float*)d_out, n);
}

// Round 5
// 408.782 us; speedup vs baseline: 1.4064x; 1.1787x over previous
//
#include <hip/hip_runtime.h>

typedef float f32x4 __attribute__((ext_vector_type(4)));
typedef __bf16 bf16x8 __attribute__((ext_vector_type(8)));
typedef __bf16 bf16x4 __attribute__((ext_vector_type(4)));

// ---- workspace layout: bf16 weight-fragment region, then f32 region ----
#define WB_W1E 0
#define WB_W2E 4096
#define WB_W3E 20480
#define WB_W1N 22528
#define WB_W2N 26624
#define WB_W3N 43008
#define WB_W1D 45056
#define WB_W2D 49152
#define WB_W3D 65536
#define WB_W4D 81920
#define WB_TOTAL 83968

// ================= weight prep: f32 row-major [K][N] -> fragmented bf16 =================
// frag fi = kt*CT+ct, within frag lane-major 8 elems:
//   value = W[klogical][ct*16 + (lane&15)], physical k = kt*32 + (lane>>4)*8 + j
//  seg0 (ew1):  p0..3 = disp/norm, p8..10 = ea, p11 = xs, p12 = xd, p13 = bias
//  seg3/6 (nw1/dw1): p0..4 = inputs, p5 = bias
__global__ void k_prep(const float* __restrict__ ew1, const float* __restrict__ eb1,
                       const float* __restrict__ ew2, const float* __restrict__ ew3,
                       const float* __restrict__ nw1, const float* __restrict__ nb1,
                       const float* __restrict__ nw2, const float* __restrict__ nw3,
                       const float* __restrict__ dw1, const float* __restrict__ db1,
                       const float* __restrict__ dw2, const float* __restrict__ dw3,
                       const float* __restrict__ dw4, __bf16* __restrict__ wb) {
  int gid = blockIdx.x * 256 + threadIdx.x;
  if (gid >= WB_TOTAL) return;
  const float* srcs[10] = {ew1, ew2, ew3, nw1, nw2, nw3, dw1, dw2, dw3, dw4};
  const float* brow[10] = {eb1, 0, 0, nb1, 0, 0, db1, 0, 0, 0};
  const int Ks[10] = {9, 128, 128, 5, 128, 128, 5, 128, 128, 128};
  const int Ns[10] = {128, 128, 3, 128, 128, 1, 128, 128, 128, 1};
  const int CTs[10] = {8, 8, 1, 8, 8, 1, 8, 8, 8, 1};
  const int cum[11] = {0, 4096, 20480, 22528, 26624, 43008, 45056, 49152, 65536, 81920, 83968};
  int seg = 0;
  while (gid >= cum[seg + 1]) seg++;
  int li = gid - cum[seg];
  int j = li & 7;
  int lane = (li >> 3) & 63;
  int fi = li >> 9;
  int CT = CTs[seg];
  int ct = fi % CT;
  int kt = fi / CT;
  int k = kt * 32 + ((lane >> 4) << 3) + j;  // physical k
  int n = ct * 16 + (lane & 15);
  int kl;  // logical row; -1 = zero, -2 = bias
  if (seg == 0) {
    if (k < 4) kl = k;
    else if (k >= 8 && k < 13) kl = k - 4;
    else kl = (k == 13) ? -2 : -1;
  } else if (seg == 3 || seg == 6) {
    if (k < 5) kl = k;
    else kl = (k == 5) ? -2 : -1;
  } else {
    kl = (k < Ks[seg]) ? k : -1;
  }
  float v = 0.f;
  if (n < Ns[seg]) {
    if (kl >= 0) v = srcs[seg][kl * Ns[seg] + n];
    else if (kl == -2 && brow[seg]) v = brow[seg][n];
  }
  wb[gid] = (__bf16)v;
}

// ================= sort-by-dst pipeline (one-time per launch) =================
__global__ void k_zero(const float* __restrict__ y_prev, float* __restrict__ x4,
                       int* __restrict__ rp, int n) {
  int i = blockIdx.x * 256 + threadIdx.x;
  if (i < n) x4[i] = y_prev[i];
  if (i <= n) rp[i] = 0;
}

__global__ void k_count(const int* __restrict__ dstp, int* __restrict__ rp, int E) {
  int e = blockIdx.x * 256 + threadIdx.x;
  if (e < E) atomicAdd(rp + dstp[e], 1);
}

// single-WG exclusive scan: rp (counts -> exclusive starts), invdeg
__global__ __attribute__((amdgpu_flat_work_group_size(1024, 1024))) void k_scan(
    int* __restrict__ rp, float* __restrict__ invdeg, int n) {
  __shared__ int sdata[1024];
  int t = threadIdx.x;
  int C = (n + 1023) >> 10;
  int base = t * C;
  int s = 0;
  for (int j = 0; j < C; j++) {
    int i = base + j;
    if (i < n) s += rp[i];
  }
  sdata[t] = s;
  __syncthreads();
  for (int off = 1; off < 1024; off <<= 1) {
    int v = sdata[t];
    int u = (t >= off) ? sdata[t - off] : 0;
    __syncthreads();
    sdata[t] = v + u;
    __syncthreads();
  }
  int run = (t == 0) ? 0 : sdata[t - 1];
  for (int j = 0; j < C; j++) {
    int i = base + j;
    if (i < n) {
      int c = rp[i];
      rp[i] = run;
      invdeg[i] = c > 0 ? 1.0f / (float)c : 0.f;
      run += c;
    }
  }
}

// scatter edges into dst-sorted arrays; after this, rp[d] = segment END of d
__global__ void k_scatter(const float* __restrict__ Xc, const float* __restrict__ y_prev,
                          const int* __restrict__ src, const int* __restrict__ dstp,
                          int* __restrict__ rp, int* __restrict__ srcS, int* __restrict__ dstS,
                          float* __restrict__ peS, float* __restrict__ eaS, int E) {
  int e = blockIdx.x * 256 + threadIdx.x;
  if (e >= E) return;
  int s = src[e], d = dstp[e];
  float dx = Xc[d * 6 + 0] - Xc[s * 6 + 0];
  float dy = Xc[d * 6 + 1] - Xc[s * 6 + 1];
  float dz = Xc[d * 6 + 2] - Xc[s * 6 + 2];
  float nr = sqrtf(dx * dx + dy * dy + dz * dz);
  float w = y_prev[d] - y_prev[s];
  int p = atomicAdd(rp + d, 1);
  srcS[p] = s;
  dstS[p] = d;
  f32x4 pv = {dx, dy, dz, nr};
  *(f32x4*)(peS + 4 * p) = pv;
  f32x4 av = {w * dx, w * dy, w * dz, 0.f};
  *(f32x4*)(eaS + 4 * p) = av;
}

// mean-aggregate contiguous eaS segments -> aggr (inv_deg pre-applied)
__global__ void k_gather(const float* __restrict__ eaS, const int* __restrict__ rp,
                         const float* __restrict__ invdeg, float* __restrict__ aggr, int n) {
  int i = blockIdx.x * 256 + threadIdx.x;
  if (i >= n) return;
  int s = (i == 0) ? 0 : rp[i - 1];
  int e = rp[i];
  f32x4 acc = {0.f, 0.f, 0.f, 0.f};
#pragma unroll 2
  for (int p = s; p < e; p++) {
    f32x4 v = *(const f32x4*)(eaS + 4 * p);
    acc[0] += v[0];
    acc[1] += v[1];
    acc[2] += v[2];
  }
  float iv = invdeg[i];
  f32x4 o = {acc[0] * iv, acc[1] * iv, acc[2] * iv, 0.f};
  *(f32x4*)(aggr + 4 * i) = o;
}

// ================= shared helpers =================
// act LDS: [64 rows][128 h] bf16, 256B row stride, XOR swizzle byte ^ ((row&7)<<4)
__device__ __forceinline__ int aoff(int row, int b) { return (row * 256 + b) ^ ((row & 7) << 4); }

// raw barrier: make LDS writes visible WITHOUT draining vmcnt (keeps prefetch in flight)
__device__ __forceinline__ void wg_sync() {
  asm volatile("s_waitcnt lgkmcnt(0)" ::: "memory");
  __builtin_amdgcn_s_barrier();
}

__device__ __forceinline__ bf16x4 relu_pack(f32x4 a) {
  bf16x4 p;
#pragma unroll
  for (int r = 0; r < 4; r++) {
    float v = a[r];
    p[r] = (__bf16)(v > 0.f ? v : 0.f);
  }
  return p;
}

// ================= edge pass: 4-wave WG, 64 edges/tile, n-sliced layers, NO atomics ==========
__global__ __attribute__((amdgpu_flat_work_group_size(256, 256), amdgpu_waves_per_eu(3, 4))) void
k_edge(const float* __restrict__ x4, const float* __restrict__ pe, float* __restrict__ ea,
       const int* __restrict__ src, const int* __restrict__ dstp,
       const __bf16* __restrict__ W1f, const __bf16* __restrict__ W2f,
       const __bf16* __restrict__ W3f, const float* __restrict__ b2,
       const float* __restrict__ b3, int ntiles, int E) {
  __shared__ char Ab[16384];
  __shared__ char Bb[16384];
  const int tid = threadIdx.x;
  const int l = tid & 63, w = tid >> 6;
  const int col = l & 15, krow = l >> 4;
  const int rl = w * 16 + (l >> 2), chunk = l & 3;  // staging row + 16B chunk

  // resident weight slices: wave w owns output cols n in [w*32, w*32+32)
  bf16x8 w1r[2], w2r[4][2], w3r[4];
#pragma unroll
  for (int t = 0; t < 2; t++) w1r[t] = *(const bf16x8*)(W1f + ((2 * w + t) << 9) + l * 8);
#pragma unroll
  for (int kt = 0; kt < 4; kt++)
#pragma unroll
    for (int t = 0; t < 2; t++)
      w2r[kt][t] = *(const bf16x8*)(W2f + ((kt * 8 + 2 * w + t) << 9) + l * 8);
#pragma unroll
  for (int kt = 0; kt < 4; kt++) w3r[kt] = *(const bf16x8*)(W3f + (kt << 9) + l * 8);
  f32x4 b2c[2];
#pragma unroll
  for (int t = 0; t < 2; t++) b2c[t] = *(const f32x4*)(b2 + (2 * w + t) * 16 + krow * 4);
  f32x4 b3i = {0.f, 0.f, 0.f, 0.f};
  if (krow == 0) {
    b3i[0] = b3[0];
    b3i[1] = b3[1];
    b3i[2] = b3[2];
  }

  int tile = blockIdx.x;
  if (tile >= ntiles) return;

  // prologue: load current tile's edge data (per-lane row rl, chunk role)
  int e0 = tile * 64 + rl;
  int ec = e0 < E ? e0 : E - 1;
  int cs = src[ec], cd = dstp[ec];
  f32x4 cld = {0.f, 0.f, 0.f, 0.f};
  if (chunk < 2) cld = *(const f32x4*)(((chunk == 1) ? ea : pe) + 4 * ec);
  float cxs = 0.f, cxd = 0.f;
  if (chunk == 1) {
    cxs = x4[cs];
    cxd = x4[cd];
  }

  for (;;) {
    // ---- stage input: chunk0=[disp,norm,0..], chunk1=[ea,xs,xd,1,0,0], chunk2/3=0 ----
    bf16x8 v;
#pragma unroll
    for (int q = 0; q < 8; q++) v[q] = (__bf16)0.f;
    if (chunk == 0) {
      v[0] = (__bf16)cld[0];
      v[1] = (__bf16)cld[1];
      v[2] = (__bf16)cld[2];
      v[3] = (__bf16)cld[3];
    } else if (chunk == 1) {
      v[0] = (__bf16)cld[0];
      v[1] = (__bf16)cld[1];
      v[2] = (__bf16)cld[2];
      v[3] = (__bf16)cxs;
      v[4] = (__bf16)cxd;
      v[5] = (__bf16)1.0f;
    }
    *(bf16x8*)(Ab + aoff(rl, chunk * 16)) = v;

    // prefetch stage A: next tile's indices
    int nt = tile + (int)gridDim.x;
    bool hn = nt < ntiles;
    int tc = hn ? nt : tile;
    int en = tc * 64 + rl;
    if (en >= E) en = E - 1;
    int ns = src[en], nd = dstp[en];

    wg_sync();  // A ready (input)

    // ---- layer1 (K=32, bias folded via 1-slot) ----
    f32x4 h[4][2];
#pragma unroll
    for (int c = 0; c < 4; c++)
#pragma unroll
      for (int t = 0; t < 2; t++) {
        f32x4 z = {0.f, 0.f, 0.f, 0.f};
        h[c][t] = z;
      }
    bf16x8 bb[4];
#pragma unroll
    for (int c = 0; c < 4; c++) bb[c] = *(const bf16x8*)(Ab + aoff(c * 16 + col, krow * 16));
#pragma unroll
    for (int c = 0; c < 4; c++)
#pragma unroll
      for (int t = 0; t < 2; t++)
        h[c][t] = __builtin_amdgcn_mfma_f32_16x16x32_bf16(w1r[t], bb[c], h[c][t], 0, 0, 0);
#pragma unroll
    for (int c = 0; c < 4; c++)
#pragma unroll
      for (int t = 0; t < 2; t++)
        *(bf16x4*)(Bb + aoff(c * 16 + col, (2 * w + t) * 32 + krow * 8)) = relu_pack(h[c][t]);

    wg_sync();  // B ready (h1)

    // prefetch stage B: dependent gathers (ns/nd arrived by now)
    f32x4 nld = {0.f, 0.f, 0.f, 0.f};
    if (chunk < 2) nld = *(const f32x4*)(((chunk == 1) ? ea : pe) + 4 * en);
    float nxs = 0.f, nxd = 0.f;
    if (chunk == 1) {
      nxs = x4[ns];
      nxd = x4[nd];
    }

    // ---- layer2 (128x128, resident slice) ----
#pragma unroll
    for (int c = 0; c < 4; c++)
#pragma unroll
      for (int t = 0; t < 2; t++) h[c][t] = b2c[t];
#pragma unroll
    for (int kt = 0; kt < 4; kt++) {
#pragma unroll
      for (int c = 0; c < 4; c++)
        bb[c] = *(const bf16x8*)(Bb + aoff(c * 16 + col, kt * 64 + krow * 16));
#pragma unroll
      for (int c = 0; c < 4; c++)
#pragma unroll
        for (int t = 0; t < 2; t++)
          h[c][t] = __builtin_amdgcn_mfma_f32_16x16x32_bf16(w2r[kt][t], bb[c], h[c][t], 0, 0, 0);
    }
#pragma unroll
    for (int c = 0; c < 4; c++)
#pragma unroll
      for (int t = 0; t < 2; t++)
        *(bf16x4*)(Ab + aoff(c * 16 + col, (2 * w + t) * 32 + krow * 8)) = relu_pack(h[c][t]);

    wg_sync();  // A ready (h2)

    // ---- layer3 (128 -> 3): wave w handles its own 16 edges ----
    f32x4 o = b3i;
#pragma unroll
    for (int kt = 0; kt < 4; kt++) {
      bf16x8 bq = *(const bf16x8*)(Ab + aoff(w * 16 + col, kt * 64 + krow * 16));
      o = __builtin_amdgcn_mfma_f32_16x16x32_bf16(w3r[kt], bq, o, 0, 0, 0);
    }

    // ---- epilogue: krow0 lane col owns edge e3; plain ea RMW, no atomics ----
    if (krow == 0) {
      int e3 = tile * 64 + w * 16 + col;
      if (e3 < E) {
        f32x4 oe = *(const f32x4*)(ea + 4 * e3);
        f32x4 nv;
        nv[0] = oe[0] + o[0];
        nv[1] = oe[1] + o[1];
        nv[2] = oe[2] + o[2];
        nv[3] = 0.f;
        *(f32x4*)(ea + 4 * e3) = nv;
      }
    }

    if (!hn) break;
    tile = nt;
    cld = nld;
    cxs = nxs;
    cxd = nxd;
  }
}

// ================= node pass: one 64-node tile per WG =================
__global__ __attribute__((amdgpu_flat_work_group_size(256, 256), amdgpu_waves_per_eu(3, 4))) void
k_node(float* __restrict__ x4, const float* __restrict__ Xc, const float* __restrict__ aggr,
       const __bf16* __restrict__ W1f, const __bf16* __restrict__ W2f,
       const __bf16* __restrict__ W3f, const float* __restrict__ b2,
       const float* __restrict__ b3, int n) {
  __shared__ char Ab[16384];
  __shared__ char Bb[16384];
  const int tid = threadIdx.x;
  const int l = tid & 63, w = tid >> 6;
  const int col = l & 15, krow = l >> 4;
  const int rl = w * 16 + (l >> 2), chunk = l & 3;

  bf16x8 w1r[2], w2r[4][2], w3r[4];
#pragma unroll
  for (int t = 0; t < 2; t++) w1r[t] = *(const bf16x8*)(W1f + ((2 * w + t) << 9) + l * 8);
#pragma unroll
  for (int kt = 0; kt < 4; kt++)
#pragma unroll
    for (int t = 0; t < 2; t++)
      w2r[kt][t] = *(const bf16x8*)(W2f + ((kt * 8 + 2 * w + t) << 9) + l * 8);
#pragma unroll
  for (int kt = 0; kt < 4; kt++) w3r[kt] = *(const bf16x8*)(W3f + (kt << 9) + l * 8);
  f32x4 b2c[2];
#pragma unroll
  for (int t = 0; t < 2; t++) b2c[t] = *(const f32x4*)(b2 + (2 * w + t) * 16 + krow * 4);
  float b3s = b3[0];

  int tile = blockIdx.x;
  int i0 = tile * 64 + rl;
  bool vi = i0 < n;
  int i = vi ? i0 : (n - 1);

  bf16x8 v;
#pragma unroll
  for (int q = 0; q < 8; q++) v[q] = (__bf16)0.f;
  if (chunk == 0) {
    float x3 = Xc[i * 6 + 4];
    float xv = x4[i];
    f32x4 ag = *(const f32x4*)(aggr + 4 * i);
    v[0] = (__bf16)x3;
    v[1] = (__bf16)xv;
    v[2] = (__bf16)ag[0];
    v[3] = (__bf16)ag[1];
    v[4] = (__bf16)ag[2];
    v[5] = (__bf16)1.0f;
  }
  *(bf16x8*)(Ab + aoff(rl, chunk * 16)) = v;

  wg_sync();

  f32x4 h[4][2];
#pragma unroll
  for (int c = 0; c < 4; c++)
#pragma unroll
    for (int t = 0; t < 2; t++) {
      f32x4 z = {0.f, 0.f, 0.f, 0.f};
      h[c][t] = z;
    }
  bf16x8 bb[4];
#pragma unroll
  for (int c = 0; c < 4; c++) bb[c] = *(const bf16x8*)(Ab + aoff(c * 16 + col, krow * 16));
#pragma unroll
  for (int c = 0; c < 4; c++)
#pragma unroll
    for (int t = 0; t < 2; t++)
      h[c][t] = __builtin_amdgcn_mfma_f32_16x16x32_bf16(w1r[t], bb[c], h[c][t], 0, 0, 0);
#pragma unroll
  for (int c = 0; c < 4; c++)
#pragma unroll
    for (int t = 0; t < 2; t++)
      *(bf16x4*)(Bb + aoff(c * 16 + col, (2 * w + t) * 32 + krow * 8)) = relu_pack(h[c][t]);

  wg_sync();

#pragma unroll
  for (int c = 0; c < 4; c++)
#pragma unroll
    for (int t = 0; t < 2; t++) h[c][t] = b2c[t];
#pragma unroll
  for (int kt = 0; kt < 4; kt++) {
#pragma unroll
    for (int c = 0; c < 4; c++)
      bb[c] = *(const bf16x8*)(Bb + aoff(c * 16 + col, kt * 64 + krow * 16));
#pragma unroll
    for (int c = 0; c < 4; c++)
#pragma unroll
      for (int t = 0; t < 2; t++)
        h[c][t] = __builtin_amdgcn_mfma_f32_16x16x32_bf16(w2r[kt][t], bb[c], h[c][t], 0, 0, 0);
  }
#pragma unroll
  for (int c = 0; c < 4; c++)
#pragma unroll
    for (int t = 0; t < 2; t++)
      *(bf16x4*)(Ab + aoff(c * 16 + col, (2 * w + t) * 32 + krow * 8)) = relu_pack(h[c][t]);

  wg_sync();

  f32x4 o = {0.f, 0.f, 0.f, 0.f};
  if (krow == 0) o[0] = b3s;
#pragma unroll
  for (int kt = 0; kt < 4; kt++) {
    bf16x8 bq = *(const bf16x8*)(Ab + aoff(w * 16 + col, kt * 64 + krow * 16));
    o = __builtin_amdgcn_mfma_f32_16x16x32_bf16(w3r[kt], bq, o, 0, 0, 0);
  }

  if (krow == 0) {
    int i3 = tile * 64 + w * 16 + col;
    if (i3 < n) x4[i3] = x4[i3] + o[0];
  }
}

// ================= decoder: one 64-node tile per WG, 4 layers =================
__global__ __attribute__((amdgpu_flat_work_group_size(256, 256), amdgpu_waves_per_eu(2, 4))) void
k_dec(const float* __restrict__ x4, const float* __restrict__ Xc, const float* __restrict__ y_prev,
      const __bf16* __restrict__ W1f, const __bf16* __restrict__ W2f,
      const __bf16* __restrict__ W3f, const __bf16* __restrict__ W4f,
      const float* __restrict__ b2, const float* __restrict__ b3, const float* __restrict__ b4,
      float* __restrict__ out, int n) {
  __shared__ char Ab[16384];
  __shared__ char Bb[16384];
  const int tid = threadIdx.x;
  const int l = tid & 63, w = tid >> 6;
  const int col = l & 15, krow = l >> 4;
  const int rl = w * 16 + (l >> 2), chunk = l & 3;

  bf16x8 w1r[2], w2r[4][2], w3r[4][2], w4r[4];
#pragma unroll
  for (int t = 0; t < 2; t++) w1r[t] = *(const bf16x8*)(W1f + ((2 * w + t) << 9) + l * 8);
#pragma unroll
  for (int kt = 0; kt < 4; kt++)
#pragma unroll
    for (int t = 0; t < 2; t++) {
      w2r[kt][t] = *(const bf16x8*)(W2f + ((kt * 8 + 2 * w + t) << 9) + l * 8);
      w3r[kt][t] = *(const bf16x8*)(W3f + ((kt * 8 + 2 * w + t) << 9) + l * 8);
    }
#pragma unroll
  for (int kt = 0; kt < 4; kt++) w4r[kt] = *(const bf16x8*)(W4f + (kt << 9) + l * 8);
  f32x4 b2c[2], b3c[2];
#pragma unroll
  for (int t = 0; t < 2; t++) {
    b2c[t] = *(const f32x4*)(b2 + (2 * w + t) * 16 + krow * 4);
    b3c[t] = *(const f32x4*)(b3 + (2 * w + t) * 16 + krow * 4);
  }
  float b4s = b4[0];

  int tile = blockIdx.x;
  int i0 = tile * 64 + rl;
  bool vi = i0 < n;
  int i = vi ? i0 : (n - 1);

  bf16x8 v;
#pragma unroll
  for (int q = 0; q < 8; q++) v[q] = (__bf16)0.f;
  if (chunk == 0) {
    v[0] = (__bf16)Xc[i * 6 + 0];
    v[1] = (__bf16)Xc[i * 6 + 1];
    v[2] = (__bf16)Xc[i * 6 + 2];
    v[3] = (__bf16)Xc[i * 6 + 4];
    v[4] = (__bf16)x4[i];
    v[5] = (__bf16)1.0f;
  }
  *(bf16x8*)(Ab + aoff(rl, chunk * 16)) = v;

  wg_sync();

  f32x4 h[4][2];
  bf16x8 bb[4];
  // layer1 -> B
#pragma unroll
  for (int c = 0; c < 4; c++)
#pragma unroll
    for (int t = 0; t < 2; t++) {
      f32x4 z = {0.f, 0.f, 0.f, 0.f};
      h[c][t] = z;
    }
#pragma unroll
  for (int c = 0; c < 4; c++) bb[c] = *(const bf16x8*)(Ab + aoff(c * 16 + col, krow * 16));
#pragma unroll
  for (int c = 0; c < 4; c++)
#pragma unroll
    for (int t = 0; t < 2; t++)
      h[c][t] = __builtin_amdgcn_mfma_f32_16x16x32_bf16(w1r[t], bb[c], h[c][t], 0, 0, 0);
#pragma unroll
  for (int c = 0; c < 4; c++)
#pragma unroll
    for (int t = 0; t < 2; t++)
      *(bf16x4*)(Bb + aoff(c * 16 + col, (2 * w + t) * 32 + krow * 8)) = relu_pack(h[c][t]);

  wg_sync();

  // layer2 -> A
#pragma unroll
  for (int c = 0; c < 4; c++)
#pragma unroll
    for (int t = 0; t < 2; t++) h[c][t] = b2c[t];
#pragma unroll
  for (int kt = 0; kt < 4; kt++) {
#pragma unroll
    for (int c = 0; c < 4; c++)
      bb[c] = *(const bf16x8*)(Bb + aoff(c * 16 + col, kt * 64 + krow * 16));
#pragma unroll
    for (int c = 0; c < 4; c++)
#pragma unroll
      for (int t = 0; t < 2; t++)
        h[c][t] = __builtin_amdgcn_mfma_f32_16x16x32_bf16(w2r[kt][t], bb[c], h[c][t], 0, 0, 0);
  }
#pragma unroll
  for (int c = 0; c < 4; c++)
#pragma unroll
    for (int t = 0; t < 2; t++)
      *(bf16x4*)(Ab + aoff(c * 16 + col, (2 * w + t) * 32 + krow * 8)) = relu_pack(h[c][t]);

  wg_sync();

  // layer3 -> B
#pragma unroll
  for (int c = 0; c < 4; c++)
#pragma unroll
    for (int t = 0; t < 2; t++) h[c][t] = b3c[t];
#pragma unroll
  for (int kt = 0; kt < 4; kt++) {
#pragma unroll
    for (int c = 0; c < 4; c++)
      bb[c] = *(const bf16x8*)(Ab + aoff(c * 16 + col, kt * 64 + krow * 16));
#pragma unroll
    for (int c = 0; c < 4; c++)
#pragma unroll
      for (int t = 0; t < 2; t++)
        h[c][t] = __builtin_amdgcn_mfma_f32_16x16x32_bf16(w3r[kt][t], bb[c], h[c][t], 0, 0, 0);
  }
#pragma unroll
  for (int c = 0; c < 4; c++)
#pragma unroll
    for (int t = 0; t < 2; t++)
      *(bf16x4*)(Bb + aoff(c * 16 + col, (2 * w + t) * 32 + krow * 8)) = relu_pack(h[c][t]);

  wg_sync();

  // layer4 (128 -> 1)
  f32x4 o = {0.f, 0.f, 0.f, 0.f};
  if (krow == 0) o[0] = b4s;
#pragma unroll
  for (int kt = 0; kt < 4; kt++) {
    bf16x8 bq = *(const bf16x8*)(Bb + aoff(w * 16 + col, kt * 64 + krow * 16));
    o = __builtin_amdgcn_mfma_f32_16x16x32_bf16(w4r[kt], bq, o, 0, 0, 0);
  }

  if (krow == 0) {
    int i3 = tile * 64 + w * 16 + col;
    if (i3 < n) out[i3] = y_prev[i3] + o[0];
  }
}

// ================= host =================
extern "C" void kernel_launch(void* const* d_in, const int* in_sizes, int n_in, void* d_out,
                              int out_size, void* d_ws, size_t ws_size, hipStream_t stream) {
  const float* Xc = (const float*)d_in[0];
  const float* y_prev = (const float*)d_in[1];
  const int* edge = (const int*)d_in[2];
  const float* ew1 = (const float*)d_in[4];
  const float* eb1 = (const float*)d_in[5];
  const float* ew2 = (const float*)d_in[6];
  const float* eb2 = (const float*)d_in[7];
  const float* ew3 = (const float*)d_in[8];
  const float* eb3 = (const float*)d_in[9];
  const float* nw1 = (const float*)d_in[10];
  const float* nb1 = (const float*)d_in[11];
  const float* nw2 = (const float*)d_in[12];
  const float* nb2 = (const float*)d_in[13];
  const float* nw3 = (const float*)d_in[14];
  const float* nb3 = (const float*)d_in[15];
  const float* dw1 = (const float*)d_in[16];
  const float* db1 = (const float*)d_in[17];
  const float* dw2 = (const float*)d_in[18];
  const float* db2 = (const float*)d_in[19];
  const float* dw3 = (const float*)d_in[20];
  const float* db3 = (const float*)d_in[21];
  const float* dw4 = (const float*)d_in[22];
  const float* db4 = (const float*)d_in[23];

  int n = in_sizes[0] / 6;
  int E = in_sizes[2] / 2;
  const int* srcp = edge;
  const int* dstp = edge + E;

  __bf16* wb = (__bf16*)d_ws;
  float* fbase = (float*)((char*)d_ws + (size_t)WB_TOTAL * 2);
  size_t na = ((size_t)n + 3) & ~(size_t)3;
  float* x4 = fbase;                 // na
  float* invdeg = fbase + na;        // na
  float* aggr = fbase + 2 * na;      // 4*na
  int* rp = (int*)(fbase + 6 * na);  // na + 8
  int* srcS = rp + na + 8;           // E
  int* dstS = srcS + E;              // E
  float* peS = (float*)(dstS + E);   // 4*E
  float* eaS = peS + 4 * (size_t)E;  // 4*E

  size_t need = (size_t)WB_TOTAL * 2 + (7 * na + 8 + 10 * (size_t)E) * 4;
  if (ws_size < need) return;  // workspace too small -> fail loudly

  dim3 B(256);
  k_prep<<<dim3((WB_TOTAL + 255) / 256), B, 0, stream>>>(ew1, eb1, ew2, ew3, nw1, nb1, nw2, nw3,
                                                         dw1, db1, dw2, dw3, dw4, wb);
  k_zero<<<dim3((n + 256) / 256), B, 0, stream>>>(y_prev, x4, rp, n);
  k_count<<<dim3((E + 255) / 256), B, 0, stream>>>(dstp, rp, E);
  k_scan<<<dim3(1), dim3(1024), 0, stream>>>(rp, invdeg, n);
  k_scatter<<<dim3((E + 255) / 256), B, 0, stream>>>(Xc, y_prev, srcp, dstp, rp, srcS, dstS, peS,
                                                     eaS, E);

  int etiles = (E + 63) / 64;
  int vtiles = (n + 63) / 64;
  int egrid = etiles < 768 ? etiles : 768;
  for (int it = 0; it < 3; it++) {
    k_edge<<<dim3(egrid), B, 0, stream>>>(x4, peS, eaS, srcS, dstS, wb + WB_W1E, wb + WB_W2E,
                                          wb + WB_W3E, eb2, eb3, etiles, E);
    k_gather<<<dim3((n + 255) / 256), B, 0, stream>>>(eaS, rp, invdeg, aggr, n);
    k_node<<<dim3(vtiles), B, 0, stream>>>(x4, Xc, aggr, wb + WB_W1N, wb + WB_W2N, wb + WB_W3N,
                                           nb2, nb3, n);
  }
  k_dec<<<dim3(vtiles), B, 0, stream>>>(x4, Xc, y_prev, wb + WB_W1D, wb + WB_W2D, wb + WB_W3D,
                                        wb + WB_W4D, db2, db3, db4, (float*)d_out, n);
}

// Round 6
// 294.715 us; speedup vs baseline: 1.9507x; 1.3870x over previous
//
#include <hip/hip_runtime.h>

typedef float f32x4 __attribute__((ext_vector_type(4)));
typedef __bf16 bf16x8 __attribute__((ext_vector_type(8)));
typedef __bf16 bf16x4 __attribute__((ext_vector_type(4)));

// ---- workspace layout: bf16 weight-fragment region, then f32 region ----
#define WB_W1E 0
#define WB_W2E 4096
#define WB_W3E 20480
#define WB_W1N 22528
#define WB_W2N 26624
#define WB_W3N 43008
#define WB_W1D 45056
#define WB_W2D 49152
#define WB_W3D 65536
#define WB_W4D 81920
#define WB_TOTAL 83968

// ================= weight prep: f32 row-major [K][N] -> fragmented bf16 =================
// frag fi = kt*CT+ct, within frag lane-major 8 elems:
//   value = W[klogical][ct*16 + (lane&15)], physical k = kt*32 + (lane>>4)*8 + j
//  seg0 (ew1):  p0..3 = disp/norm, p8..10 = ea, p11 = xs, p12 = xd, p13 = bias
//  seg3/6 (nw1/dw1): p0..4 = inputs, p5 = bias
__global__ void k_prep(const float* __restrict__ ew1, const float* __restrict__ eb1,
                       const float* __restrict__ ew2, const float* __restrict__ ew3,
                       const float* __restrict__ nw1, const float* __restrict__ nb1,
                       const float* __restrict__ nw2, const float* __restrict__ nw3,
                       const float* __restrict__ dw1, const float* __restrict__ db1,
                       const float* __restrict__ dw2, const float* __restrict__ dw3,
                       const float* __restrict__ dw4, __bf16* __restrict__ wb) {
  int gid = blockIdx.x * 256 + threadIdx.x;
  if (gid >= WB_TOTAL) return;
  const float* srcs[10] = {ew1, ew2, ew3, nw1, nw2, nw3, dw1, dw2, dw3, dw4};
  const float* brow[10] = {eb1, 0, 0, nb1, 0, 0, db1, 0, 0, 0};
  const int Ks[10] = {9, 128, 128, 5, 128, 128, 5, 128, 128, 128};
  const int Ns[10] = {128, 128, 3, 128, 128, 1, 128, 128, 128, 1};
  const int CTs[10] = {8, 8, 1, 8, 8, 1, 8, 8, 8, 1};
  const int cum[11] = {0, 4096, 20480, 22528, 26624, 43008, 45056, 49152, 65536, 81920, 83968};
  int seg = 0;
  while (gid >= cum[seg + 1]) seg++;
  int li = gid - cum[seg];
  int j = li & 7;
  int lane = (li >> 3) & 63;
  int fi = li >> 9;
  int CT = CTs[seg];
  int ct = fi % CT;
  int kt = fi / CT;
  int k = kt * 32 + ((lane >> 4) << 3) + j;  // physical k
  int n = ct * 16 + (lane & 15);
  int kl;  // logical row; -1 = zero, -2 = bias
  if (seg == 0) {
    if (k < 4) kl = k;
    else if (k >= 8 && k < 13) kl = k - 4;
    else kl = (k == 13) ? -2 : -1;
  } else if (seg == 3 || seg == 6) {
    if (k < 5) kl = k;
    else kl = (k == 5) ? -2 : -1;
  } else {
    kl = (k < Ks[seg]) ? k : -1;
  }
  float v = 0.f;
  if (n < Ns[seg]) {
    if (kl >= 0) v = srcs[seg][kl * Ns[seg] + n];
    else if (kl == -2 && brow[seg]) v = brow[seg][n];
  }
  wb[gid] = (__bf16)v;
}

// ================= sort-by-dst pipeline (one-time per launch) =================
__global__ void k_zero(const float* __restrict__ y_prev, float* __restrict__ x4,
                       int* __restrict__ cnt, int n) {
  int i = blockIdx.x * 256 + threadIdx.x;
  if (i < n) {
    x4[i] = y_prev[i];
    cnt[i] = 0;
  }
}

__global__ void k_count(const int* __restrict__ dstp, int* __restrict__ cnt, int E) {
  int e = blockIdx.x * 256 + threadIdx.x;
  if (e < E) atomicAdd(cnt + dstp[e], 1);
}

// two-level parallel exclusive scan: block phase
__global__ void k_scan_block(const int* __restrict__ cnt, int* __restrict__ rp,
                             float* __restrict__ invdeg, int* __restrict__ bsum, int n) {
  __shared__ int sd[256];
  int t = threadIdx.x;
  int i = blockIdx.x * 256 + t;
  int c = (i < n) ? cnt[i] : 0;
  if (i < n) invdeg[i] = c > 0 ? 1.0f / (float)c : 0.f;
  sd[t] = c;
  __syncthreads();
#pragma unroll
  for (int off = 1; off < 256; off <<= 1) {
    int v = sd[t];
    int u = (t >= off) ? sd[t - off] : 0;
    __syncthreads();
    sd[t] = v + u;
    __syncthreads();
  }
  if (i < n) rp[i] = sd[t] - c;  // exclusive within block
  if (t == 255) bsum[blockIdx.x] = sd[255];
}

// top-level scan of block sums (nb <= 1024), single block
__global__ void k_scan_top(int* __restrict__ bsum, int nb) {
  __shared__ int sd[1024];
  int t = threadIdx.x;
  int c = (t < nb) ? bsum[t] : 0;
  sd[t] = c;
  __syncthreads();
#pragma unroll
  for (int off = 1; off < 1024; off <<= 1) {
    int v = sd[t];
    int u = (t >= off) ? sd[t - off] : 0;
    __syncthreads();
    sd[t] = v + u;
    __syncthreads();
  }
  if (t < nb) bsum[t] = sd[t] - c;  // exclusive
}

__global__ void k_scan_add(int* __restrict__ rp, const int* __restrict__ bsum, int n) {
  int i = blockIdx.x * 256 + threadIdx.x;
  if (i < n) rp[i] += bsum[blockIdx.x];
}

// scatter edges into dst-sorted arrays; after this, rp[d] = segment END of d
__global__ void k_scatter(const float* __restrict__ Xc, const float* __restrict__ y_prev,
                          const int* __restrict__ src, const int* __restrict__ dstp,
                          int* __restrict__ rp, int* __restrict__ srcS, int* __restrict__ dstS,
                          float* __restrict__ peS, float* __restrict__ eaS, int E) {
  int e = blockIdx.x * 256 + threadIdx.x;
  if (e >= E) return;
  int s = src[e], d = dstp[e];
  float dx = Xc[d * 6 + 0] - Xc[s * 6 + 0];
  float dy = Xc[d * 6 + 1] - Xc[s * 6 + 1];
  float dz = Xc[d * 6 + 2] - Xc[s * 6 + 2];
  float nr = sqrtf(dx * dx + dy * dy + dz * dz);
  float w = y_prev[d] - y_prev[s];
  int p = atomicAdd(rp + d, 1);
  srcS[p] = s;
  dstS[p] = d;
  f32x4 pv = {dx, dy, dz, nr};
  *(f32x4*)(peS + 4 * p) = pv;
  f32x4 av = {w * dx, w * dy, w * dz, 0.f};
  *(f32x4*)(eaS + 4 * p) = av;
}

// mean-aggregate contiguous eaS segments -> aggr (inv_deg pre-applied)
__global__ void k_gather(const float* __restrict__ eaS, const int* __restrict__ rp,
                         const float* __restrict__ invdeg, float* __restrict__ aggr, int n) {
  int i = blockIdx.x * 256 + threadIdx.x;
  if (i >= n) return;
  int s = (i == 0) ? 0 : rp[i - 1];
  int e = rp[i];
  f32x4 acc = {0.f, 0.f, 0.f, 0.f};
#pragma unroll 2
  for (int p = s; p < e; p++) {
    f32x4 v = *(const f32x4*)(eaS + 4 * p);
    acc[0] += v[0];
    acc[1] += v[1];
    acc[2] += v[2];
  }
  float iv = invdeg[i];
  f32x4 o = {acc[0] * iv, acc[1] * iv, acc[2] * iv, 0.f};
  *(f32x4*)(aggr + 4 * i) = o;
}

// ================= shared helpers =================
// act LDS: [64 rows][128 h] bf16, 256B row stride, XOR swizzle byte ^ ((row&7)<<4)
__device__ __forceinline__ int aoff(int row, int b) { return (row * 256 + b) ^ ((row & 7) << 4); }

// raw barrier: make LDS writes visible WITHOUT draining vmcnt (keeps prefetch in flight)
__device__ __forceinline__ void wg_sync() {
  asm volatile("s_waitcnt lgkmcnt(0)" ::: "memory");
  __builtin_amdgcn_s_barrier();
}

__device__ __forceinline__ bf16x4 relu_pack(f32x4 a) {
  bf16x4 p;
#pragma unroll
  for (int r = 0; r < 4; r++) {
    float v = a[r];
    p[r] = (__bf16)(v > 0.f ? v : 0.f);
  }
  return p;
}

// ================= edge pass: 4-wave WG, 64 edges/tile, n-sliced layers, NO atomics ==========
__global__ __attribute__((amdgpu_flat_work_group_size(256, 256), amdgpu_waves_per_eu(3, 4))) void
k_edge(const float* __restrict__ x4, const float* __restrict__ pe, float* __restrict__ ea,
       const int* __restrict__ src, const int* __restrict__ dstp,
       const __bf16* __restrict__ W1f, const __bf16* __restrict__ W2f,
       const __bf16* __restrict__ W3f, const float* __restrict__ b2,
       const float* __restrict__ b3, int ntiles, int E) {
  __shared__ char Ab[16384];
  __shared__ char Bb[16384];
  const int tid = threadIdx.x;
  const int l = tid & 63, w = tid >> 6;
  const int col = l & 15, krow = l >> 4;
  const int rl = w * 16 + (l >> 2), chunk = l & 3;  // staging row + 16B chunk

  // resident weight slices: wave w owns output cols n in [w*32, w*32+32)
  bf16x8 w1r[2], w2r[4][2], w3r[4];
#pragma unroll
  for (int t = 0; t < 2; t++) w1r[t] = *(const bf16x8*)(W1f + ((2 * w + t) << 9) + l * 8);
#pragma unroll
  for (int kt = 0; kt < 4; kt++)
#pragma unroll
    for (int t = 0; t < 2; t++)
      w2r[kt][t] = *(const bf16x8*)(W2f + ((kt * 8 + 2 * w + t) << 9) + l * 8);
#pragma unroll
  for (int kt = 0; kt < 4; kt++) w3r[kt] = *(const bf16x8*)(W3f + (kt << 9) + l * 8);
  f32x4 b2c[2];
#pragma unroll
  for (int t = 0; t < 2; t++) b2c[t] = *(const f32x4*)(b2 + (2 * w + t) * 16 + krow * 4);
  f32x4 b3i = {0.f, 0.f, 0.f, 0.f};
  if (krow == 0) {
    b3i[0] = b3[0];
    b3i[1] = b3[1];
    b3i[2] = b3[2];
  }

  int tile = blockIdx.x;
  if (tile >= ntiles) return;

  // prologue: load current tile's edge data (per-lane row rl, chunk role)
  int e0 = tile * 64 + rl;
  int ec = e0 < E ? e0 : E - 1;
  int cs = src[ec], cd = dstp[ec];
  f32x4 cld = {0.f, 0.f, 0.f, 0.f};
  if (chunk < 2) cld = *(const f32x4*)(((chunk == 1) ? ea : pe) + 4 * ec);
  float cxs = 0.f, cxd = 0.f;
  if (chunk == 1) {
    cxs = x4[cs];
    cxd = x4[cd];
  }

  for (;;) {
    // ---- stage input: chunk0=[disp,norm,0..], chunk1=[ea,xs,xd,1,0,0], chunk2/3=0 ----
    bf16x8 v;
#pragma unroll
    for (int q = 0; q < 8; q++) v[q] = (__bf16)0.f;
    if (chunk == 0) {
      v[0] = (__bf16)cld[0];
      v[1] = (__bf16)cld[1];
      v[2] = (__bf16)cld[2];
      v[3] = (__bf16)cld[3];
    } else if (chunk == 1) {
      v[0] = (__bf16)cld[0];
      v[1] = (__bf16)cld[1];
      v[2] = (__bf16)cld[2];
      v[3] = (__bf16)cxs;
      v[4] = (__bf16)cxd;
      v[5] = (__bf16)1.0f;
    }
    *(bf16x8*)(Ab + aoff(rl, chunk * 16)) = v;

    // prefetch stage A: next tile's indices
    int nt = tile + (int)gridDim.x;
    bool hn = nt < ntiles;
    int tc = hn ? nt : tile;
    int en = tc * 64 + rl;
    if (en >= E) en = E - 1;
    int ns = src[en], nd = dstp[en];

    wg_sync();  // A ready (input)

    // ---- layer1 (K=32, bias folded via 1-slot) ----
    f32x4 h[4][2];
#pragma unroll
    for (int c = 0; c < 4; c++)
#pragma unroll
      for (int t = 0; t < 2; t++) {
        f32x4 z = {0.f, 0.f, 0.f, 0.f};
        h[c][t] = z;
      }
    bf16x8 bb[4];
#pragma unroll
    for (int c = 0; c < 4; c++) bb[c] = *(const bf16x8*)(Ab + aoff(c * 16 + col, krow * 16));
#pragma unroll
    for (int c = 0; c < 4; c++)
#pragma unroll
      for (int t = 0; t < 2; t++)
        h[c][t] = __builtin_amdgcn_mfma_f32_16x16x32_bf16(w1r[t], bb[c], h[c][t], 0, 0, 0);
#pragma unroll
    for (int c = 0; c < 4; c++)
#pragma unroll
      for (int t = 0; t < 2; t++)
        *(bf16x4*)(Bb + aoff(c * 16 + col, (2 * w + t) * 32 + krow * 8)) = relu_pack(h[c][t]);

    wg_sync();  // B ready (h1)

    // prefetch stage B: dependent gathers (ns/nd arrived by now)
    f32x4 nld = {0.f, 0.f, 0.f, 0.f};
    if (chunk < 2) nld = *(const f32x4*)(((chunk == 1) ? ea : pe) + 4 * en);
    float nxs = 0.f, nxd = 0.f;
    if (chunk == 1) {
      nxs = x4[ns];
      nxd = x4[nd];
    }

    // ---- layer2 (128x128, resident slice) ----
#pragma unroll
    for (int c = 0; c < 4; c++)
#pragma unroll
      for (int t = 0; t < 2; t++) h[c][t] = b2c[t];
#pragma unroll
    for (int kt = 0; kt < 4; kt++) {
#pragma unroll
      for (int c = 0; c < 4; c++)
        bb[c] = *(const bf16x8*)(Bb + aoff(c * 16 + col, kt * 64 + krow * 16));
#pragma unroll
      for (int c = 0; c < 4; c++)
#pragma unroll
        for (int t = 0; t < 2; t++)
          h[c][t] = __builtin_amdgcn_mfma_f32_16x16x32_bf16(w2r[kt][t], bb[c], h[c][t], 0, 0, 0);
    }
#pragma unroll
    for (int c = 0; c < 4; c++)
#pragma unroll
      for (int t = 0; t < 2; t++)
        *(bf16x4*)(Ab + aoff(c * 16 + col, (2 * w + t) * 32 + krow * 8)) = relu_pack(h[c][t]);

    wg_sync();  // A ready (h2)

    // ---- layer3 (128 -> 3): wave w handles its own 16 edges ----
    f32x4 o = b3i;
#pragma unroll
    for (int kt = 0; kt < 4; kt++) {
      bf16x8 bq = *(const bf16x8*)(Ab + aoff(w * 16 + col, kt * 64 + krow * 16));
      o = __builtin_amdgcn_mfma_f32_16x16x32_bf16(w3r[kt], bq, o, 0, 0, 0);
    }

    // ---- epilogue: krow0 lane col owns edge e3; plain ea RMW, no atomics ----
    if (krow == 0) {
      int e3 = tile * 64 + w * 16 + col;
      if (e3 < E) {
        f32x4 oe = *(const f32x4*)(ea + 4 * e3);
        f32x4 nv;
        nv[0] = oe[0] + o[0];
        nv[1] = oe[1] + o[1];
        nv[2] = oe[2] + o[2];
        nv[3] = 0.f;
        *(f32x4*)(ea + 4 * e3) = nv;
      }
    }

    if (!hn) break;
    tile = nt;
    cld = nld;
    cxs = nxs;
    cxd = nxd;
  }
}

// ================= node pass: one 64-node tile per WG =================
__global__ __attribute__((amdgpu_flat_work_group_size(256, 256), amdgpu_waves_per_eu(3, 4))) void
k_node(float* __restrict__ x4, const float* __restrict__ Xc, const float* __restrict__ aggr,
       const __bf16* __restrict__ W1f, const __bf16* __restrict__ W2f,
       const __bf16* __restrict__ W3f, const float* __restrict__ b2,
       const float* __restrict__ b3, int n) {
  __shared__ char Ab[16384];
  __shared__ char Bb[16384];
  const int tid = threadIdx.x;
  const int l = tid & 63, w = tid >> 6;
  const int col = l & 15, krow = l >> 4;
  const int rl = w * 16 + (l >> 2), chunk = l & 3;

  bf16x8 w1r[2], w2r[4][2], w3r[4];
#pragma unroll
  for (int t = 0; t < 2; t++) w1r[t] = *(const bf16x8*)(W1f + ((2 * w + t) << 9) + l * 8);
#pragma unroll
  for (int kt = 0; kt < 4; kt++)
#pragma unroll
    for (int t = 0; t < 2; t++)
      w2r[kt][t] = *(const bf16x8*)(W2f + ((kt * 8 + 2 * w + t) << 9) + l * 8);
#pragma unroll
  for (int kt = 0; kt < 4; kt++) w3r[kt] = *(const bf16x8*)(W3f + (kt << 9) + l * 8);
  f32x4 b2c[2];
#pragma unroll
  for (int t = 0; t < 2; t++) b2c[t] = *(const f32x4*)(b2 + (2 * w + t) * 16 + krow * 4);
  float b3s = b3[0];

  int tile = blockIdx.x;
  int i0 = tile * 64 + rl;
  bool vi = i0 < n;
  int i = vi ? i0 : (n - 1);

  bf16x8 v;
#pragma unroll
  for (int q = 0; q < 8; q++) v[q] = (__bf16)0.f;
  if (chunk == 0) {
    float x3 = Xc[i * 6 + 4];
    float xv = x4[i];
    f32x4 ag = *(const f32x4*)(aggr + 4 * i);
    v[0] = (__bf16)x3;
    v[1] = (__bf16)xv;
    v[2] = (__bf16)ag[0];
    v[3] = (__bf16)ag[1];
    v[4] = (__bf16)ag[2];
    v[5] = (__bf16)1.0f;
  }
  *(bf16x8*)(Ab + aoff(rl, chunk * 16)) = v;

  wg_sync();

  f32x4 h[4][2];
#pragma unroll
  for (int c = 0; c < 4; c++)
#pragma unroll
    for (int t = 0; t < 2; t++) {
      f32x4 z = {0.f, 0.f, 0.f, 0.f};
      h[c][t] = z;
    }
  bf16x8 bb[4];
#pragma unroll
  for (int c = 0; c < 4; c++) bb[c] = *(const bf16x8*)(Ab + aoff(c * 16 + col, krow * 16));
#pragma unroll
  for (int c = 0; c < 4; c++)
#pragma unroll
    for (int t = 0; t < 2; t++)
      h[c][t] = __builtin_amdgcn_mfma_f32_16x16x32_bf16(w1r[t], bb[c], h[c][t], 0, 0, 0);
#pragma unroll
  for (int c = 0; c < 4; c++)
#pragma unroll
    for (int t = 0; t < 2; t++)
      *(bf16x4*)(Bb + aoff(c * 16 + col, (2 * w + t) * 32 + krow * 8)) = relu_pack(h[c][t]);

  wg_sync();

#pragma unroll
  for (int c = 0; c < 4; c++)
#pragma unroll
    for (int t = 0; t < 2; t++) h[c][t] = b2c[t];
#pragma unroll
  for (int kt = 0; kt < 4; kt++) {
#pragma unroll
    for (int c = 0; c < 4; c++)
      bb[c] = *(const bf16x8*)(Bb + aoff(c * 16 + col, kt * 64 + krow * 16));
#pragma unroll
    for (int c = 0; c < 4; c++)
#pragma unroll
      for (int t = 0; t < 2; t++)
        h[c][t] = __builtin_amdgcn_mfma_f32_16x16x32_bf16(w2r[kt][t], bb[c], h[c][t], 0, 0, 0);
  }
#pragma unroll
  for (int c = 0; c < 4; c++)
#pragma unroll
    for (int t = 0; t < 2; t++)
      *(bf16x4*)(Ab + aoff(c * 16 + col, (2 * w + t) * 32 + krow * 8)) = relu_pack(h[c][t]);

  wg_sync();

  f32x4 o = {0.f, 0.f, 0.f, 0.f};
  if (krow == 0) o[0] = b3s;
#pragma unroll
  for (int kt = 0; kt < 4; kt++) {
    bf16x8 bq = *(const bf16x8*)(Ab + aoff(w * 16 + col, kt * 64 + krow * 16));
    o = __builtin_amdgcn_mfma_f32_16x16x32_bf16(w3r[kt], bq, o, 0, 0, 0);
  }

  if (krow == 0) {
    int i3 = tile * 64 + w * 16 + col;
    if (i3 < n) x4[i3] = x4[i3] + o[0];
  }
}

// ================= decoder: one 64-node tile per WG, 4 layers =================
__global__ __attribute__((amdgpu_flat_work_group_size(256, 256), amdgpu_waves_per_eu(2, 4))) void
k_dec(const float* __restrict__ x4, const float* __restrict__ Xc, const float* __restrict__ y_prev,
      const __bf16* __restrict__ W1f, const __bf16* __restrict__ W2f,
      const __bf16* __restrict__ W3f, const __bf16* __restrict__ W4f,
      const float* __restrict__ b2, const float* __restrict__ b3, const float* __restrict__ b4,
      float* __restrict__ out, int n) {
  __shared__ char Ab[16384];
  __shared__ char Bb[16384];
  const int tid = threadIdx.x;
  const int l = tid & 63, w = tid >> 6;
  const int col = l & 15, krow = l >> 4;
  const int rl = w * 16 + (l >> 2), chunk = l & 3;

  bf16x8 w1r[2], w2r[4][2], w3r[4][2], w4r[4];
#pragma unroll
  for (int t = 0; t < 2; t++) w1r[t] = *(const bf16x8*)(W1f + ((2 * w + t) << 9) + l * 8);
#pragma unroll
  for (int kt = 0; kt < 4; kt++)
#pragma unroll
    for (int t = 0; t < 2; t++) {
      w2r[kt][t] = *(const bf16x8*)(W2f + ((kt * 8 + 2 * w + t) << 9) + l * 8);
      w3r[kt][t] = *(const bf16x8*)(W3f + ((kt * 8 + 2 * w + t) << 9) + l * 8);
    }
#pragma unroll
  for (int kt = 0; kt < 4; kt++) w4r[kt] = *(const bf16x8*)(W4f + (kt << 9) + l * 8);
  f32x4 b2c[2], b3c[2];
#pragma unroll
  for (int t = 0; t < 2; t++) {
    b2c[t] = *(const f32x4*)(b2 + (2 * w + t) * 16 + krow * 4);
    b3c[t] = *(const f32x4*)(b3 + (2 * w + t) * 16 + krow * 4);
  }
  float b4s = b4[0];

  int tile = blockIdx.x;
  int i0 = tile * 64 + rl;
  bool vi = i0 < n;
  int i = vi ? i0 : (n - 1);

  bf16x8 v;
#pragma unroll
  for (int q = 0; q < 8; q++) v[q] = (__bf16)0.f;
  if (chunk == 0) {
    v[0] = (__bf16)Xc[i * 6 + 0];
    v[1] = (__bf16)Xc[i * 6 + 1];
    v[2] = (__bf16)Xc[i * 6 + 2];
    v[3] = (__bf16)Xc[i * 6 + 4];
    v[4] = (__bf16)x4[i];
    v[5] = (__bf16)1.0f;
  }
  *(bf16x8*)(Ab + aoff(rl, chunk * 16)) = v;

  wg_sync();

  f32x4 h[4][2];
  bf16x8 bb[4];
  // layer1 -> B
#pragma unroll
  for (int c = 0; c < 4; c++)
#pragma unroll
    for (int t = 0; t < 2; t++) {
      f32x4 z = {0.f, 0.f, 0.f, 0.f};
      h[c][t] = z;
    }
#pragma unroll
  for (int c = 0; c < 4; c++) bb[c] = *(const bf16x8*)(Ab + aoff(c * 16 + col, krow * 16));
#pragma unroll
  for (int c = 0; c < 4; c++)
#pragma unroll
    for (int t = 0; t < 2; t++)
      h[c][t] = __builtin_amdgcn_mfma_f32_16x16x32_bf16(w1r[t], bb[c], h[c][t], 0, 0, 0);
#pragma unroll
  for (int c = 0; c < 4; c++)
#pragma unroll
    for (int t = 0; t < 2; t++)
      *(bf16x4*)(Bb + aoff(c * 16 + col, (2 * w + t) * 32 + krow * 8)) = relu_pack(h[c][t]);

  wg_sync();

  // layer2 -> A
#pragma unroll
  for (int c = 0; c < 4; c++)
#pragma unroll
    for (int t = 0; t < 2; t++) h[c][t] = b2c[t];
#pragma unroll
  for (int kt = 0; kt < 4; kt++) {
#pragma unroll
    for (int c = 0; c < 4; c++)
      bb[c] = *(const bf16x8*)(Bb + aoff(c * 16 + col, kt * 64 + krow * 16));
#pragma unroll
    for (int c = 0; c < 4; c++)
#pragma unroll
      for (int t = 0; t < 2; t++)
        h[c][t] = __builtin_amdgcn_mfma_f32_16x16x32_bf16(w2r[kt][t], bb[c], h[c][t], 0, 0, 0);
  }
#pragma unroll
  for (int c = 0; c < 4; c++)
#pragma unroll
    for (int t = 0; t < 2; t++)
      *(bf16x4*)(Ab + aoff(c * 16 + col, (2 * w + t) * 32 + krow * 8)) = relu_pack(h[c][t]);

  wg_sync();

  // layer3 -> B
#pragma unroll
  for (int c = 0; c < 4; c++)
#pragma unroll
    for (int t = 0; t < 2; t++) h[c][t] = b3c[t];
#pragma unroll
  for (int kt = 0; kt < 4; kt++) {
#pragma unroll
    for (int c = 0; c < 4; c++)
      bb[c] = *(const bf16x8*)(Ab + aoff(c * 16 + col, kt * 64 + krow * 16));
#pragma unroll
    for (int c = 0; c < 4; c++)
#pragma unroll
      for (int t = 0; t < 2; t++)
        h[c][t] = __builtin_amdgcn_mfma_f32_16x16x32_bf16(w3r[kt][t], bb[c], h[c][t], 0, 0, 0);
  }
#pragma unroll
  for (int c = 0; c < 4; c++)
#pragma unroll
    for (int t = 0; t < 2; t++)
      *(bf16x4*)(Bb + aoff(c * 16 + col, (2 * w + t) * 32 + krow * 8)) = relu_pack(h[c][t]);

  wg_sync();

  // layer4 (128 -> 1)
  f32x4 o = {0.f, 0.f, 0.f, 0.f};
  if (krow == 0) o[0] = b4s;
#pragma unroll
  for (int kt = 0; kt < 4; kt++) {
    bf16x8 bq = *(const bf16x8*)(Bb + aoff(w * 16 + col, kt * 64 + krow * 16));
    o = __builtin_amdgcn_mfma_f32_16x16x32_bf16(w4r[kt], bq, o, 0, 0, 0);
  }

  if (krow == 0) {
    int i3 = tile * 64 + w * 16 + col;
    if (i3 < n) out[i3] = y_prev[i3] + o[0];
  }
}

// ================= host =================
extern "C" void kernel_launch(void* const* d_in, const int* in_sizes, int n_in, void* d_out,
                              int out_size, void* d_ws, size_t ws_size, hipStream_t stream) {
  const float* Xc = (const float*)d_in[0];
  const float* y_prev = (const float*)d_in[1];
  const int* edge = (const int*)d_in[2];
  const float* ew1 = (const float*)d_in[4];
  const float* eb1 = (const float*)d_in[5];
  const float* ew2 = (const float*)d_in[6];
  const float* eb2 = (const float*)d_in[7];
  const float* ew3 = (const float*)d_in[8];
  const float* eb3 = (const float*)d_in[9];
  const float* nw1 = (const float*)d_in[10];
  const float* nb1 = (const float*)d_in[11];
  const float* nw2 = (const float*)d_in[12];
  const float* nb2 = (const float*)d_in[13];
  const float* nw3 = (const float*)d_in[14];
  const float* nb3 = (const float*)d_in[15];
  const float* dw1 = (const float*)d_in[16];
  const float* db1 = (const float*)d_in[17];
  const float* dw2 = (const float*)d_in[18];
  const float* db2 = (const float*)d_in[19];
  const float* dw3 = (const float*)d_in[20];
  const float* db3 = (const float*)d_in[21];
  const float* dw4 = (const float*)d_in[22];
  const float* db4 = (const float*)d_in[23];

  int n = in_sizes[0] / 6;
  int E = in_sizes[2] / 2;
  const int* srcp = edge;
  const int* dstp = edge + E;

  __bf16* wb = (__bf16*)d_ws;
  float* fbase = (float*)((char*)d_ws + (size_t)WB_TOTAL * 2);
  size_t na = ((size_t)n + 3) & ~(size_t)3;
  float* x4 = fbase;                  // na
  float* invdeg = fbase + na;         // na
  float* aggr = fbase + 2 * na;       // 4*na
  int* cnt = (int*)(fbase + 6 * na);  // na
  int* rp = cnt + na;                 // na + 8
  int* bsum = rp + na + 8;            // 1024
  int* srcS = bsum + 1024;            // E
  int* dstS = srcS + E;               // E
  float* peS = (float*)(dstS + E);    // 4*E
  float* eaS = peS + 4 * (size_t)E;   // 4*E

  size_t need = (size_t)WB_TOTAL * 2 + (8 * na + 8 + 1024 + 10 * (size_t)E) * 4;
  if (ws_size < need) return;  // workspace too small -> fail loudly

  dim3 B(256);
  int nblk = (n + 255) / 256;  // 196 for n=50000 (must be <= 1024)
  k_prep<<<dim3((WB_TOTAL + 255) / 256), B, 0, stream>>>(ew1, eb1, ew2, ew3, nw1, nb1, nw2, nw3,
                                                         dw1, db1, dw2, dw3, dw4, wb);
  k_zero<<<dim3(nblk), B, 0, stream>>>(y_prev, x4, cnt, n);
  k_count<<<dim3((E + 255) / 256), B, 0, stream>>>(dstp, cnt, E);
  k_scan_block<<<dim3(nblk), B, 0, stream>>>(cnt, rp, invdeg, bsum, n);
  k_scan_top<<<dim3(1), dim3(1024), 0, stream>>>(bsum, nblk);
  k_scan_add<<<dim3(nblk), B, 0, stream>>>(rp, bsum, n);
  k_scatter<<<dim3((E + 255) / 256), B, 0, stream>>>(Xc, y_prev, srcp, dstp, rp, srcS, dstS, peS,
                                                     eaS, E);

  int etiles = (E + 63) / 64;
  int vtiles = (n + 63) / 64;
  int egrid = etiles < 768 ? etiles : 768;
  for (int it = 0; it < 3; it++) {
    k_edge<<<dim3(egrid), B, 0, stream>>>(x4, peS, eaS, srcS, dstS, wb + WB_W1E, wb + WB_W2E,
                                          wb + WB_W3E, eb2, eb3, etiles, E);
    k_gather<<<dim3((n + 255) / 256), B, 0, stream>>>(eaS, rp, invdeg, aggr, n);
    k_node<<<dim3(vtiles), B, 0, stream>>>(x4, Xc, aggr, wb + WB_W1N, wb + WB_W2N, wb + WB_W3N,
                                           nb2, nb3, n);
  }
  k_dec<<<dim3(vtiles), B, 0, stream>>>(x4, Xc, y_prev, wb + WB_W1D, wb + WB_W2D, wb + WB_W3D,
                                        wb + WB_W4D, db2, db3, db4, (float*)d_out, n);
}